// Round 11
// baseline (172.991 us; speedup 1.0000x reference)
//
#include <hip/hip_runtime.h>

#define NN   1601
#define EMB  300
#define NB   2048
#define L    64
#define TSTR 304   // t0bf / T / E1 row stride (elements)
#define S    72    // LDS matrix stride (u16) -> 144B rows, 16B-aligned frags

typedef __attribute__((ext_vector_type(8))) short bf16x8;
typedef __attribute__((ext_vector_type(4))) float f32x4;

static __device__ __forceinline__ ushort f2b(float x) {
  union { float f; unsigned u; } c; c.f = x;
  unsigned u = c.u;
  return (ushort)((u + 0x7FFFu + ((u >> 16) & 1u)) >> 16);   // RNE
}
static __device__ __forceinline__ float b2f(ushort h) {
  union { unsigned u; float f; } c; c.u = ((unsigned)h) << 16; return c.f;
}

#define LD8(p, r, c) (*(const bf16x8*)&(p)[(size_t)(r) * S + (c)])
#define MFMA(a, bm, acc) __builtin_amdgcn_mfma_f32_16x16x32_bf16((a), (bm), (acc), 0, 0, 0)

// ---------------------------------------------------------------------------
// 4-buffer GEMM body (k_pre1 only): C = A@B^T (BT=1) or A@B (BT=0),
// hi/lo bf16 3-term MFMA (~f32). One 64x64 tile per call.
// ---------------------------------------------------------------------------
template <int BT, int BF16OUT>
__device__ __forceinline__ void gemm_body(ushort* arena,
                                          const float* __restrict__ A,
                                          const float* __restrict__ B,
                                          void* __restrict__ Cout,
                                          int M, int AS, int BS, int KG,
                                          int mb, int nb) {
  ushort* Ahi = arena;
  ushort* Alo = arena + L * S;
  ushort* Bhi = arena + 2 * L * S;
  ushort* Blo = arena + 3 * L * S;
  int tid = threadIdx.x;
  int lane = tid & 63, w = tid >> 6;
  int lrow = lane & 15, lk = lane >> 4;

  f32x4 acc[4];
  #pragma unroll
  for (int t = 0; t < 4; ++t) acc[t] = (f32x4){0.f, 0.f, 0.f, 0.f};

  for (int kc = 0; kc < 5; ++kc) {
    int k0 = 64 * kc;
    for (int idx = tid; idx < 64 * 16; idx += 256) {
      int r = idx >> 4, c4 = (idx & 15) * 4;
      int m = mb * 64 + r, k = k0 + c4;
      float4 v = make_float4(0.f, 0.f, 0.f, 0.f);
      if (m < M && k < KG) v = *(const float4*)&A[(size_t)m * AS + k];
      ushort4 h4, l4;
      h4.x = f2b(v.x); l4.x = f2b(v.x - b2f(h4.x));
      h4.y = f2b(v.y); l4.y = f2b(v.y - b2f(h4.y));
      h4.z = f2b(v.z); l4.z = f2b(v.z - b2f(h4.z));
      h4.w = f2b(v.w); l4.w = f2b(v.w - b2f(h4.w));
      *(ushort4*)&Ahi[r * S + c4] = h4;
      *(ushort4*)&Alo[r * S + c4] = l4;
    }
    for (int idx = tid; idx < 64 * 16; idx += 256) {
      int r = idx >> 4, c4 = (idx & 15) * 4;
      if (BT) {
        int n = nb * 64 + r, k = k0 + c4;
        float4 v = make_float4(0.f, 0.f, 0.f, 0.f);
        if (n < 300 && k < 300) v = *(const float4*)&B[(size_t)n * BS + k];
        ushort4 h4, l4;
        h4.x = f2b(v.x); l4.x = f2b(v.x - b2f(h4.x));
        h4.y = f2b(v.y); l4.y = f2b(v.y - b2f(h4.y));
        h4.z = f2b(v.z); l4.z = f2b(v.z - b2f(h4.z));
        h4.w = f2b(v.w); l4.w = f2b(v.w - b2f(h4.w));
        *(ushort4*)&Bhi[r * S + c4] = h4;
        *(ushort4*)&Blo[r * S + c4] = l4;
      } else {
        int k = k0 + r, n = nb * 64 + c4;
        float4 v = make_float4(0.f, 0.f, 0.f, 0.f);
        if (k < 300 && n < 300) v = *(const float4*)&B[(size_t)k * BS + n];
        #pragma unroll
        for (int q = 0; q < 4; ++q) {
          float xq = (q == 0) ? v.x : (q == 1) ? v.y : (q == 2) ? v.z : v.w;
          ushort hi = f2b(xq);
          Bhi[(size_t)(c4 + q) * S + r] = hi;
          Blo[(size_t)(c4 + q) * S + r] = f2b(xq - b2f(hi));
        }
      }
    }
    __syncthreads();
    #pragma unroll
    for (int ks = 0; ks < 2; ++ks) {
      bf16x8 ah = LD8(Ahi, 16 * w + lrow, 32 * ks + 8 * lk);
      bf16x8 al = LD8(Alo, 16 * w + lrow, 32 * ks + 8 * lk);
      #pragma unroll
      for (int t = 0; t < 4; ++t) {
        bf16x8 bh = LD8(Bhi, 16 * t + lrow, 32 * ks + 8 * lk);
        bf16x8 bl = LD8(Blo, 16 * t + lrow, 32 * ks + 8 * lk);
        acc[t] = MFMA(ah, bh, acc[t]);
        acc[t] = MFMA(ah, bl, acc[t]);
        acc[t] = MFMA(al, bh, acc[t]);
      }
    }
    __syncthreads();
  }
  #pragma unroll
  for (int t = 0; t < 4; ++t) {
    int n = nb * 64 + 16 * t + lrow;
    int mbase = mb * 64 + 16 * w + 4 * lk;
    if (n < TSTR) {
      #pragma unroll
      for (int r = 0; r < 4; ++r) {
        int m = mbase + r;
        if (m < M) {
          if (BF16OUT) ((ushort*)Cout)[(size_t)m * TSTR + n] = f2b(acc[t][r]);
          else         ((float*)Cout)[(size_t)m * TSTR + n] = acc[t][r];
        }
      }
    }
  }
}

// ---------------------------------------------------------------------------
// 2-buffer GEMM body (k_pre2's t0bf = E1 @ T^T, bf16 out). Same arithmetic,
// A-frags pass through regs so only 2 LDS buffers are needed (4 bars/kc).
// ---------------------------------------------------------------------------
__device__ __forceinline__ void gemm2_body(ushort* arena,
                                           const float* __restrict__ A,
                                           const float* __restrict__ B,
                                           ushort* __restrict__ Cout,
                                           int M, int mb, int nb) {
  ushort* buf0 = arena;
  ushort* buf1 = arena + L * S;
  int tid = threadIdx.x;
  int lane = tid & 63, w = tid >> 6;
  int lrow = lane & 15, lk = lane >> 4;

  f32x4 acc[4];
  #pragma unroll
  for (int t = 0; t < 4; ++t) acc[t] = (f32x4){0.f, 0.f, 0.f, 0.f};

  for (int kc = 0; kc < 5; ++kc) {
    int k0 = 64 * kc;
    // stage A tile hi/lo
    for (int idx = tid; idx < 64 * 16; idx += 256) {
      int r = idx >> 4, c4 = (idx & 15) * 4;
      int m = mb * 64 + r, k = k0 + c4;
      float4 v = make_float4(0.f, 0.f, 0.f, 0.f);
      if (m < M && k < TSTR) v = *(const float4*)&A[(size_t)m * TSTR + k];
      ushort4 h4, l4;
      h4.x = f2b(v.x); l4.x = f2b(v.x - b2f(h4.x));
      h4.y = f2b(v.y); l4.y = f2b(v.y - b2f(h4.y));
      h4.z = f2b(v.z); l4.z = f2b(v.z - b2f(h4.z));
      h4.w = f2b(v.w); l4.w = f2b(v.w - b2f(h4.w));
      *(ushort4*)&buf0[r * S + c4] = h4;
      *(ushort4*)&buf1[r * S + c4] = l4;
    }
    __syncthreads();
    bf16x8 ah0 = LD8(buf0, 16 * w + lrow, 8 * lk);
    bf16x8 ah1 = LD8(buf0, 16 * w + lrow, 32 + 8 * lk);
    bf16x8 al0 = LD8(buf1, 16 * w + lrow, 8 * lk);
    bf16x8 al1 = LD8(buf1, 16 * w + lrow, 32 + 8 * lk);
    __syncthreads();
    // stage B tile hi/lo (B^T operand: frag[n][k] = B[n][k], B stride TSTR)
    for (int idx = tid; idx < 64 * 16; idx += 256) {
      int r = idx >> 4, c4 = (idx & 15) * 4;
      int n = nb * 64 + r, k = k0 + c4;
      float4 v = make_float4(0.f, 0.f, 0.f, 0.f);
      if (n < 300 && k < TSTR) v = *(const float4*)&B[(size_t)n * TSTR + k];
      ushort4 h4, l4;
      h4.x = f2b(v.x); l4.x = f2b(v.x - b2f(h4.x));
      h4.y = f2b(v.y); l4.y = f2b(v.y - b2f(h4.y));
      h4.z = f2b(v.z); l4.z = f2b(v.z - b2f(h4.z));
      h4.w = f2b(v.w); l4.w = f2b(v.w - b2f(h4.w));
      *(ushort4*)&buf0[r * S + c4] = h4;
      *(ushort4*)&buf1[r * S + c4] = l4;
    }
    __syncthreads();
    #pragma unroll
    for (int t = 0; t < 4; ++t) {
      bf16x8 bh = LD8(buf0, 16 * t + lrow, 8 * lk);
      bf16x8 bl = LD8(buf1, 16 * t + lrow, 8 * lk);
      acc[t] = MFMA(ah0, bh, acc[t]);
      acc[t] = MFMA(ah0, bl, acc[t]);
      acc[t] = MFMA(al0, bh, acc[t]);
      bh = LD8(buf0, 16 * t + lrow, 32 + 8 * lk);
      bl = LD8(buf1, 16 * t + lrow, 32 + 8 * lk);
      acc[t] = MFMA(ah1, bh, acc[t]);
      acc[t] = MFMA(ah1, bl, acc[t]);
      acc[t] = MFMA(al1, bh, acc[t]);
    }
    __syncthreads();
  }
  #pragma unroll
  for (int t = 0; t < 4; ++t) {
    int n = nb * 64 + 16 * t + lrow;
    int mbase = mb * 64 + 16 * w + 4 * lk;
    if (n < TSTR) {
      #pragma unroll
      for (int r = 0; r < 4; ++r) {
        int m = mbase + r;
        if (m < M) Cout[(size_t)m * TSTR + n] = f2b(acc[t][r]);
      }
    }
  }
}

// ---------------------------------------------------------------------------
// Launch 1: [0,25) T = W3@W2 | [25,155) E1 = emb@W1^T | [155,1179) u8 quant
// ---------------------------------------------------------------------------
__global__ __launch_bounds__(256, 4) void k_pre1(const float* __restrict__ in_adj,
                                                 unsigned char* __restrict__ adj8,
                                                 const float* __restrict__ emb,
                                                 const float* __restrict__ lw,
                                                 float* __restrict__ E1,
                                                 float* __restrict__ T) {
  __shared__ __align__(16) ushort arena[4 * L * S];
  const float* W1 = lw;
  const float* W2 = lw + (size_t)EMB * EMB;
  const float* W3 = lw + 2 * (size_t)EMB * EMB;
  int bid = blockIdx.x;
  if (bid < 25) {
    gemm_body<0, 0>(arena, W3, W2, T, 300, 300, 300, 300, bid / 5, bid % 5);
  } else if (bid < 155) {
    int rid = bid - 25;
    gemm_body<1, 0>(arena, emb, W1, E1, NN, 300, 300, 300, rid % 26, rid / 26);
  } else {
    int b2 = bid - 155;
    const int total = NN * NN;           // 2563201
    const int n4 = total >> 2;
    int i = b2 * 256 + threadIdx.x;
    for (int i4 = i; i4 < n4; i4 += 1024 * 256) {
      float4 v = *(const float4*)&in_adj[4 * i4];
      uchar4 q;
      q.x = (unsigned char)__float2int_rn(v.x * 255.f);
      q.y = (unsigned char)__float2int_rn(v.y * 255.f);
      q.z = (unsigned char)__float2int_rn(v.z * 255.f);
      q.w = (unsigned char)__float2int_rn(v.w * 255.f);
      *(uchar4*)&adj8[4 * i4] = q;
    }
    if (i == 0)
      adj8[total - 1] = (unsigned char)__float2int_rn(in_adj[total - 1] * 255.f);
  }
}

// ---------------------------------------------------------------------------
// A^3 body, 2-buffer LDS: A = norm(gather_u8 + I); A2 = A@A; A3 = A@A2,
// hi/lo 3-term MFMA. Writes A3 (64x64 bf16 rows) to a3g[b].
// ---------------------------------------------------------------------------
__device__ __forceinline__ void a3_body(ushort* arena, int* lab, float (*ps)[L],
                                        float* dv, const int* __restrict__ labels,
                                        const unsigned char* __restrict__ adj8,
                                        ushort* __restrict__ a3g, int b) {
  ushort* buf0 = arena;
  ushort* buf1 = arena + L * S;
  int tid = threadIdx.x, j = tid & 63, g = tid >> 6;
  if (tid < L) lab[tid] = labels[(size_t)b * L + tid];
  __syncthreads();
  int labj = lab[j];

  float raw[16];
  float cs = 0.f;
  #pragma unroll
  for (int q = 0; q < 16; ++q) {
    int i = g + 4 * q;
    float v = (float)adj8[(size_t)lab[i] * NN + labj];
    v += (i == j) ? 255.f : 0.f;
    raw[q] = v; cs += v;
  }
  ps[g][j] = cs;
  __syncthreads();
  if (tid < L) dv[tid] = 1.f / sqrtf(ps[0][tid] + ps[1][tid] + ps[2][tid] + ps[3][tid]);
  __syncthreads();

  // A rows (hi/lo) into buf0/buf1; keep scaled values in regs
  float dj = dv[j];
  #pragma unroll
  for (int q = 0; q < 16; ++q) {
    int i = g + 4 * q;
    float a = raw[q] * dv[i] * dj;
    raw[q] = a;
    ushort hi = f2b(a);
    buf0[(size_t)i * S + j] = hi;
    buf1[(size_t)i * S + j] = f2b(a - b2f(hi));
  }
  __syncthreads();

  int lane = tid & 63, w = tid >> 6;
  int lrow = lane & 15, lk = lane >> 4;
  int m0 = 16 * w;

  bf16x8 ah0 = LD8(buf0, m0 + lrow, 8 * lk);
  bf16x8 ah1 = LD8(buf0, m0 + lrow, 32 + 8 * lk);
  bf16x8 al0 = LD8(buf1, m0 + lrow, 8 * lk);
  bf16x8 al1 = LD8(buf1, m0 + lrow, 32 + 8 * lk);
  __syncthreads();

  // overwrite with A^T (hi/lo)
  #pragma unroll
  for (int q = 0; q < 16; ++q) {
    int i = g + 4 * q;
    float a = raw[q];
    ushort hi = f2b(a);
    buf0[(size_t)j * S + i] = hi;
    buf1[(size_t)j * S + i] = f2b(a - b2f(hi));
  }
  __syncthreads();

  // A2 = A @ A -> overwrite buf0/1 with A2^T
  {
    f32x4 acc[4];
    #pragma unroll
    for (int t = 0; t < 4; ++t) {
      f32x4 a = {0.f, 0.f, 0.f, 0.f};
      bf16x8 bh = LD8(buf0, 16 * t + lrow, 8 * lk);
      bf16x8 bl = LD8(buf1, 16 * t + lrow, 8 * lk);
      a = MFMA(ah0, bh, a); a = MFMA(ah0, bl, a); a = MFMA(al0, bh, a);
      bh = LD8(buf0, 16 * t + lrow, 32 + 8 * lk);
      bl = LD8(buf1, 16 * t + lrow, 32 + 8 * lk);
      a = MFMA(ah1, bh, a); a = MFMA(ah1, bl, a); a = MFMA(al1, bh, a);
      acc[t] = a;
    }
    __syncthreads();
    #pragma unroll
    for (int t = 0; t < 4; ++t) {
      ushort4 h4, l4;
      float x;
      x = acc[t][0]; h4.x = f2b(x); l4.x = f2b(x - b2f(h4.x));
      x = acc[t][1]; h4.y = f2b(x); l4.y = f2b(x - b2f(h4.y));
      x = acc[t][2]; h4.z = f2b(x); l4.z = f2b(x - b2f(h4.z));
      x = acc[t][3]; h4.w = f2b(x); l4.w = f2b(x - b2f(h4.w));
      *(ushort4*)&buf0[(size_t)(16 * t + lrow) * S + m0 + 4 * lk] = h4;
      *(ushort4*)&buf1[(size_t)(16 * t + lrow) * S + m0 + 4 * lk] = l4;
    }
  }
  __syncthreads();

  // A3 = A @ A2 -> rows into buf0
  {
    f32x4 acc[4];
    #pragma unroll
    for (int t = 0; t < 4; ++t) {
      f32x4 a = {0.f, 0.f, 0.f, 0.f};
      bf16x8 bh = LD8(buf0, 16 * t + lrow, 8 * lk);
      bf16x8 bl = LD8(buf1, 16 * t + lrow, 8 * lk);
      a = MFMA(ah0, bh, a); a = MFMA(ah0, bl, a); a = MFMA(al0, bh, a);
      bh = LD8(buf0, 16 * t + lrow, 32 + 8 * lk);
      bl = LD8(buf1, 16 * t + lrow, 32 + 8 * lk);
      a = MFMA(ah1, bh, a); a = MFMA(ah1, bl, a); a = MFMA(al1, bh, a);
      acc[t] = a;
    }
    __syncthreads();
    #pragma unroll
    for (int t = 0; t < 4; ++t)
      #pragma unroll
      for (int r = 0; r < 4; ++r)
        buf0[(size_t)(m0 + 4 * lk + r) * S + 16 * t + lrow] = f2b(acc[t][r]);
  }
  __syncthreads();

  // coalesced store: a3g[b] = 64x64 bf16 row-major (8 KB)
  int4* dst = (int4*)(a3g + (size_t)b * (L * L));
  #pragma unroll
  for (int q = 0; q < 2; ++q) {
    int id = tid + 256 * q;
    int r = id >> 3, c8 = (id & 7) << 3;
    dst[id] = *(const int4*)&buf0[(size_t)r * S + c8];
  }
}

// ---------------------------------------------------------------------------
// Launch 2: [0,130) t0bf = E1 @ T^T (bf16, 2-buf)  |  [130,2178) A^3
// (t0bf tiles first so they don't tail the launch)
// ---------------------------------------------------------------------------
__global__ __launch_bounds__(256, 8) void k_pre2(const int* __restrict__ labels,
                                                 const unsigned char* __restrict__ adj8,
                                                 ushort* __restrict__ a3g,
                                                 const float* __restrict__ E1,
                                                 const float* __restrict__ T,
                                                 ushort* __restrict__ t0bf) {
  __shared__ __align__(16) ushort arena[2 * L * S];   // 18.4 KB
  __shared__ int   lab[L];
  __shared__ float ps[4][L];
  __shared__ float dv[L];
  int bid = blockIdx.x;
  if (bid < 130) {
    gemm2_body(arena, E1, T, t0bf, NN, bid % 26, bid / 26);
  } else {
    a3_body(arena, lab, ps, dv, labels, adj8, a3g, bid - 130);
  }
}

// ---------------------------------------------------------------------------
// Launch 3: out tiles. grid 8192: b = bid>>2, e-chunk c = bid&3.
// Stage A3[b] + Tt chunk, 1 barrier, MFMA, nontemporal full-line f32x4 stores.
// ---------------------------------------------------------------------------
__global__ __launch_bounds__(256, 7) void k_out(const int* __restrict__ labels,
                                                const ushort* __restrict__ a3g,
                                                const ushort* __restrict__ t0bf,
                                                float* __restrict__ out) {
  __shared__ __align__(16) ushort A3L[L * S];    // 9216 B
  __shared__ __align__(16) ushort Tt[80 * S];    // 11520 B
  int bid = blockIdx.x;
  int b = bid >> 2, c = bid & 3;
  int tid = threadIdx.x, j = tid & 63, g = tid >> 6;
  int labj = labels[(size_t)b * L + j];

  // stage A3 rows (coalesced int4)
  const int4* a3p = (const int4*)(a3g + (size_t)b * (L * L));
  #pragma unroll
  for (int q = 0; q < 2; ++q) {
    int id = tid + 256 * q;
    int r = id >> 3, c8 = (id & 7) << 3;
    *(int4*)&A3L[(size_t)r * S + c8] = a3p[id];
  }
  // stage Tt[e_local][j] = t0bf[lab[j]][80c + e_local]
  int base = 80 * c;
  int rows80 = (c == 3) ? 64 : 80;
  const ushort* trow = t0bf + (size_t)labj * TSTR + base;
  for (int e = 8 * g; e < rows80; e += 32) {
    union { int4 v; ushort u[8]; } uu;
    uu.v = *(const int4*)(trow + e);
    #pragma unroll
    for (int q = 0; q < 8; ++q) Tt[(size_t)(e + q) * S + j] = uu.u[q];
  }
  __syncthreads();

  int lane = tid & 63, w = tid >> 6;
  int lrow = lane & 15, lk = lane >> 4;
  int m0 = 16 * w;
  bf16x8 fb0 = LD8(A3L, m0 + lrow, 8 * lk);
  bf16x8 fb1 = LD8(A3L, m0 + lrow, 32 + 8 * lk);
  float* orow = out + ((size_t)b * L + m0 + lrow) * EMB;

  int nt = (c == 3) ? 4 : 5;
  for (int t = 0; t < nt; ++t) {
    bf16x8 a0 = LD8(Tt, 16 * t + lrow, 8 * lk);
    bf16x8 a1 = LD8(Tt, 16 * t + lrow, 32 + 8 * lk);
    f32x4 o = {0.f, 0.f, 0.f, 0.f};
    o = MFMA(a0, fb0, o);
    o = MFMA(a1, fb1, o);
    int e0 = base + 16 * t + 4 * lk;
    if (e0 < EMB) __builtin_nontemporal_store(o, (f32x4*)&orow[e0]);
  }
}

// ---------------------------------------------------------------------------
extern "C" void kernel_launch(void* const* d_in, const int* in_sizes, int n_in,
                              void* d_out, int out_size, void* d_ws, size_t ws_size,
                              hipStream_t stream) {
  (void)in_sizes; (void)n_in; (void)out_size; (void)ws_size;
  const int*   labels = (const int*)d_in[0];
  const float* in_adj = (const float*)d_in[1];
  const float* emb    = (const float*)d_in[2];
  const float* lw     = (const float*)d_in[3];
  float* out = (float*)d_out;

  char* base = (char*)d_ws;
  unsigned char* adj8 = (unsigned char*)base;              // 2,563,201 B
  float*  T    = (float*)(base + 2563216);                 // 300x304 f32
  float*  E1   = (float*)(base + 2928016);                 // 1601x304 f32
  ushort* t0bf = (ushort*)(base + 4874832);                // 1601x304 bf16
  ushort* a3g  = (ushort*)(base + 5848240);                // 2048x64x64 bf16

  k_pre1<<<1179, 256, 0, stream>>>(in_adj, adj8, emb, lw, E1, T);
  k_pre2<<<2178, 256, 0, stream>>>(labels, adj8, a3g, E1, T, t0bf);
  k_out <<<4 * NB, 256, 0, stream>>>(labels, a3g, t0bf, out);
}

// Round 12
// 101.893 us; speedup vs baseline: 1.6978x; 1.6978x over previous
//
#include <hip/hip_runtime.h>

#define NN   1601
#define EMB  300
#define NB   2048
#define L    64
#define TSTR 304   // t0bf / T / E1 row stride (elements)
#define S    72    // LDS matrix stride (u16) -> 144B rows, 16B-aligned frags

typedef __attribute__((ext_vector_type(8))) short bf16x8;
typedef __attribute__((ext_vector_type(4))) float f32x4;

static __device__ __forceinline__ ushort f2b(float x) {
  union { float f; unsigned u; } c; c.f = x;
  unsigned u = c.u;
  return (ushort)((u + 0x7FFFu + ((u >> 16) & 1u)) >> 16);   // RNE
}
static __device__ __forceinline__ float b2f(ushort h) {
  union { unsigned u; float f; } c; c.u = ((unsigned)h) << 16; return c.f;
}

#define LD8(p, r, c) (*(const bf16x8*)&(p)[(size_t)(r) * S + (c)])
#define MFMA(a, bm, acc) __builtin_amdgcn_mfma_f32_16x16x32_bf16((a), (bm), (acc), 0, 0, 0)

// ---------------------------------------------------------------------------
// 4-buffer GEMM body (k_pre1 only): C = A@B^T (BT=1) or A@B (BT=0),
// hi/lo bf16 3-term MFMA (~f32). One 64x64 tile per call.
// ---------------------------------------------------------------------------
template <int BT, int BF16OUT>
__device__ __forceinline__ void gemm_body(ushort* arena,
                                          const float* __restrict__ A,
                                          const float* __restrict__ B,
                                          void* __restrict__ Cout,
                                          int M, int AS, int BS, int KG,
                                          int mb, int nb) {
  ushort* Ahi = arena;
  ushort* Alo = arena + L * S;
  ushort* Bhi = arena + 2 * L * S;
  ushort* Blo = arena + 3 * L * S;
  int tid = threadIdx.x;
  int lane = tid & 63, w = tid >> 6;
  int lrow = lane & 15, lk = lane >> 4;

  f32x4 acc[4];
  #pragma unroll
  for (int t = 0; t < 4; ++t) acc[t] = (f32x4){0.f, 0.f, 0.f, 0.f};

  for (int kc = 0; kc < 5; ++kc) {
    int k0 = 64 * kc;
    for (int idx = tid; idx < 64 * 16; idx += 256) {
      int r = idx >> 4, c4 = (idx & 15) * 4;
      int m = mb * 64 + r, k = k0 + c4;
      float4 v = make_float4(0.f, 0.f, 0.f, 0.f);
      if (m < M && k < KG) v = *(const float4*)&A[(size_t)m * AS + k];
      ushort4 h4, l4;
      h4.x = f2b(v.x); l4.x = f2b(v.x - b2f(h4.x));
      h4.y = f2b(v.y); l4.y = f2b(v.y - b2f(h4.y));
      h4.z = f2b(v.z); l4.z = f2b(v.z - b2f(h4.z));
      h4.w = f2b(v.w); l4.w = f2b(v.w - b2f(h4.w));
      *(ushort4*)&Ahi[r * S + c4] = h4;
      *(ushort4*)&Alo[r * S + c4] = l4;
    }
    for (int idx = tid; idx < 64 * 16; idx += 256) {
      int r = idx >> 4, c4 = (idx & 15) * 4;
      if (BT) {
        int n = nb * 64 + r, k = k0 + c4;
        float4 v = make_float4(0.f, 0.f, 0.f, 0.f);
        if (n < 300 && k < 300) v = *(const float4*)&B[(size_t)n * BS + k];
        ushort4 h4, l4;
        h4.x = f2b(v.x); l4.x = f2b(v.x - b2f(h4.x));
        h4.y = f2b(v.y); l4.y = f2b(v.y - b2f(h4.y));
        h4.z = f2b(v.z); l4.z = f2b(v.z - b2f(h4.z));
        h4.w = f2b(v.w); l4.w = f2b(v.w - b2f(h4.w));
        *(ushort4*)&Bhi[r * S + c4] = h4;
        *(ushort4*)&Blo[r * S + c4] = l4;
      } else {
        int k = k0 + r, n = nb * 64 + c4;
        float4 v = make_float4(0.f, 0.f, 0.f, 0.f);
        if (k < 300 && n < 300) v = *(const float4*)&B[(size_t)k * BS + n];
        #pragma unroll
        for (int q = 0; q < 4; ++q) {
          float xq = (q == 0) ? v.x : (q == 1) ? v.y : (q == 2) ? v.z : v.w;
          ushort hi = f2b(xq);
          Bhi[(size_t)(c4 + q) * S + r] = hi;
          Blo[(size_t)(c4 + q) * S + r] = f2b(xq - b2f(hi));
        }
      }
    }
    __syncthreads();
    #pragma unroll
    for (int ks = 0; ks < 2; ++ks) {
      bf16x8 ah = LD8(Ahi, 16 * w + lrow, 32 * ks + 8 * lk);
      bf16x8 al = LD8(Alo, 16 * w + lrow, 32 * ks + 8 * lk);
      #pragma unroll
      for (int t = 0; t < 4; ++t) {
        bf16x8 bh = LD8(Bhi, 16 * t + lrow, 32 * ks + 8 * lk);
        bf16x8 bl = LD8(Blo, 16 * t + lrow, 32 * ks + 8 * lk);
        acc[t] = MFMA(ah, bh, acc[t]);
        acc[t] = MFMA(ah, bl, acc[t]);
        acc[t] = MFMA(al, bh, acc[t]);
      }
    }
    __syncthreads();
  }
  #pragma unroll
  for (int t = 0; t < 4; ++t) {
    int n = nb * 64 + 16 * t + lrow;
    int mbase = mb * 64 + 16 * w + 4 * lk;
    if (n < TSTR) {
      #pragma unroll
      for (int r = 0; r < 4; ++r) {
        int m = mbase + r;
        if (m < M) {
          if (BF16OUT) ((ushort*)Cout)[(size_t)m * TSTR + n] = f2b(acc[t][r]);
          else         ((float*)Cout)[(size_t)m * TSTR + n] = acc[t][r];
        }
      }
    }
  }
}

// ---------------------------------------------------------------------------
// 2-buffer GEMM body (k_pre2's t0bf = E1 @ T^T, bf16 out). Same arithmetic,
// A-frags pass through regs so only 2 LDS buffers are needed (4 bars/kc).
// ---------------------------------------------------------------------------
__device__ __forceinline__ void gemm2_body(ushort* arena,
                                           const float* __restrict__ A,
                                           const float* __restrict__ B,
                                           ushort* __restrict__ Cout,
                                           int M, int mb, int nb) {
  ushort* buf0 = arena;
  ushort* buf1 = arena + L * S;
  int tid = threadIdx.x;
  int lane = tid & 63, w = tid >> 6;
  int lrow = lane & 15, lk = lane >> 4;

  f32x4 acc[4];
  #pragma unroll
  for (int t = 0; t < 4; ++t) acc[t] = (f32x4){0.f, 0.f, 0.f, 0.f};

  for (int kc = 0; kc < 5; ++kc) {
    int k0 = 64 * kc;
    // stage A tile hi/lo
    for (int idx = tid; idx < 64 * 16; idx += 256) {
      int r = idx >> 4, c4 = (idx & 15) * 4;
      int m = mb * 64 + r, k = k0 + c4;
      float4 v = make_float4(0.f, 0.f, 0.f, 0.f);
      if (m < M && k < TSTR) v = *(const float4*)&A[(size_t)m * TSTR + k];
      ushort4 h4, l4;
      h4.x = f2b(v.x); l4.x = f2b(v.x - b2f(h4.x));
      h4.y = f2b(v.y); l4.y = f2b(v.y - b2f(h4.y));
      h4.z = f2b(v.z); l4.z = f2b(v.z - b2f(h4.z));
      h4.w = f2b(v.w); l4.w = f2b(v.w - b2f(h4.w));
      *(ushort4*)&buf0[r * S + c4] = h4;
      *(ushort4*)&buf1[r * S + c4] = l4;
    }
    __syncthreads();
    bf16x8 ah0 = LD8(buf0, 16 * w + lrow, 8 * lk);
    bf16x8 ah1 = LD8(buf0, 16 * w + lrow, 32 + 8 * lk);
    bf16x8 al0 = LD8(buf1, 16 * w + lrow, 8 * lk);
    bf16x8 al1 = LD8(buf1, 16 * w + lrow, 32 + 8 * lk);
    __syncthreads();
    // stage B tile hi/lo (B^T operand: frag[n][k] = B[n][k], B stride TSTR)
    for (int idx = tid; idx < 64 * 16; idx += 256) {
      int r = idx >> 4, c4 = (idx & 15) * 4;
      int n = nb * 64 + r, k = k0 + c4;
      float4 v = make_float4(0.f, 0.f, 0.f, 0.f);
      if (n < 300 && k < TSTR) v = *(const float4*)&B[(size_t)n * TSTR + k];
      ushort4 h4, l4;
      h4.x = f2b(v.x); l4.x = f2b(v.x - b2f(h4.x));
      h4.y = f2b(v.y); l4.y = f2b(v.y - b2f(h4.y));
      h4.z = f2b(v.z); l4.z = f2b(v.z - b2f(h4.z));
      h4.w = f2b(v.w); l4.w = f2b(v.w - b2f(h4.w));
      *(ushort4*)&buf0[r * S + c4] = h4;
      *(ushort4*)&buf1[r * S + c4] = l4;
    }
    __syncthreads();
    #pragma unroll
    for (int t = 0; t < 4; ++t) {
      bf16x8 bh = LD8(buf0, 16 * t + lrow, 8 * lk);
      bf16x8 bl = LD8(buf1, 16 * t + lrow, 8 * lk);
      acc[t] = MFMA(ah0, bh, acc[t]);
      acc[t] = MFMA(ah0, bl, acc[t]);
      acc[t] = MFMA(al0, bh, acc[t]);
      bh = LD8(buf0, 16 * t + lrow, 32 + 8 * lk);
      bl = LD8(buf1, 16 * t + lrow, 32 + 8 * lk);
      acc[t] = MFMA(ah1, bh, acc[t]);
      acc[t] = MFMA(ah1, bl, acc[t]);
      acc[t] = MFMA(al1, bh, acc[t]);
    }
    __syncthreads();
  }
  #pragma unroll
  for (int t = 0; t < 4; ++t) {
    int n = nb * 64 + 16 * t + lrow;
    int mbase = mb * 64 + 16 * w + 4 * lk;
    if (n < TSTR) {
      #pragma unroll
      for (int r = 0; r < 4; ++r) {
        int m = mbase + r;
        if (m < M) Cout[(size_t)m * TSTR + n] = f2b(acc[t][r]);
      }
    }
  }
}

// ---------------------------------------------------------------------------
// Launch 1: [0,25) T = W3@W2 | [25,155) E1 = emb@W1^T | [155,1179) u8 quant
// ---------------------------------------------------------------------------
__global__ __launch_bounds__(256, 4) void k_pre1(const float* __restrict__ in_adj,
                                                 unsigned char* __restrict__ adj8,
                                                 const float* __restrict__ emb,
                                                 const float* __restrict__ lw,
                                                 float* __restrict__ E1,
                                                 float* __restrict__ T) {
  __shared__ __align__(16) ushort arena[4 * L * S];
  const float* W1 = lw;
  const float* W2 = lw + (size_t)EMB * EMB;
  const float* W3 = lw + 2 * (size_t)EMB * EMB;
  int bid = blockIdx.x;
  if (bid < 25) {
    gemm_body<0, 0>(arena, W3, W2, T, 300, 300, 300, 300, bid / 5, bid % 5);
  } else if (bid < 155) {
    int rid = bid - 25;
    gemm_body<1, 0>(arena, emb, W1, E1, NN, 300, 300, 300, rid % 26, rid / 26);
  } else {
    int b2 = bid - 155;
    const int total = NN * NN;           // 2563201
    const int n4 = total >> 2;
    int i = b2 * 256 + threadIdx.x;
    for (int i4 = i; i4 < n4; i4 += 1024 * 256) {
      float4 v = *(const float4*)&in_adj[4 * i4];
      uchar4 q;
      q.x = (unsigned char)__float2int_rn(v.x * 255.f);
      q.y = (unsigned char)__float2int_rn(v.y * 255.f);
      q.z = (unsigned char)__float2int_rn(v.z * 255.f);
      q.w = (unsigned char)__float2int_rn(v.w * 255.f);
      *(uchar4*)&adj8[4 * i4] = q;
    }
    if (i == 0)
      adj8[total - 1] = (unsigned char)__float2int_rn(in_adj[total - 1] * 255.f);
  }
}

// ---------------------------------------------------------------------------
// A^3 body, 2-buffer LDS: A = norm(gather_u8 + I); A2 = A@A; A3 = A@A2,
// hi/lo 3-term MFMA. Writes A3 (64x64 bf16 rows) to a3g[b].
// ---------------------------------------------------------------------------
__device__ __forceinline__ void a3_body(ushort* arena, int* lab, float (*ps)[L],
                                        float* dv, const int* __restrict__ labels,
                                        const unsigned char* __restrict__ adj8,
                                        ushort* __restrict__ a3g, int b) {
  ushort* buf0 = arena;
  ushort* buf1 = arena + L * S;
  int tid = threadIdx.x, j = tid & 63, g = tid >> 6;
  if (tid < L) lab[tid] = labels[(size_t)b * L + tid];
  __syncthreads();
  int labj = lab[j];

  float raw[16];
  float cs = 0.f;
  #pragma unroll
  for (int q = 0; q < 16; ++q) {
    int i = g + 4 * q;
    float v = (float)adj8[(size_t)lab[i] * NN + labj];
    v += (i == j) ? 255.f : 0.f;
    raw[q] = v; cs += v;
  }
  ps[g][j] = cs;
  __syncthreads();
  if (tid < L) dv[tid] = 1.f / sqrtf(ps[0][tid] + ps[1][tid] + ps[2][tid] + ps[3][tid]);
  __syncthreads();

  // A rows (hi/lo) into buf0/buf1; keep scaled values in regs
  float dj = dv[j];
  #pragma unroll
  for (int q = 0; q < 16; ++q) {
    int i = g + 4 * q;
    float a = raw[q] * dv[i] * dj;
    raw[q] = a;
    ushort hi = f2b(a);
    buf0[(size_t)i * S + j] = hi;
    buf1[(size_t)i * S + j] = f2b(a - b2f(hi));
  }
  __syncthreads();

  int lane = tid & 63, w = tid >> 6;
  int lrow = lane & 15, lk = lane >> 4;
  int m0 = 16 * w;

  bf16x8 ah0 = LD8(buf0, m0 + lrow, 8 * lk);
  bf16x8 ah1 = LD8(buf0, m0 + lrow, 32 + 8 * lk);
  bf16x8 al0 = LD8(buf1, m0 + lrow, 8 * lk);
  bf16x8 al1 = LD8(buf1, m0 + lrow, 32 + 8 * lk);
  __syncthreads();

  // overwrite with A^T (hi/lo)
  #pragma unroll
  for (int q = 0; q < 16; ++q) {
    int i = g + 4 * q;
    float a = raw[q];
    ushort hi = f2b(a);
    buf0[(size_t)j * S + i] = hi;
    buf1[(size_t)j * S + i] = f2b(a - b2f(hi));
  }
  __syncthreads();

  // A2 = A @ A -> overwrite buf0/1 with A2^T
  {
    f32x4 acc[4];
    #pragma unroll
    for (int t = 0; t < 4; ++t) {
      f32x4 a = {0.f, 0.f, 0.f, 0.f};
      bf16x8 bh = LD8(buf0, 16 * t + lrow, 8 * lk);
      bf16x8 bl = LD8(buf1, 16 * t + lrow, 8 * lk);
      a = MFMA(ah0, bh, a); a = MFMA(ah0, bl, a); a = MFMA(al0, bh, a);
      bh = LD8(buf0, 16 * t + lrow, 32 + 8 * lk);
      bl = LD8(buf1, 16 * t + lrow, 32 + 8 * lk);
      a = MFMA(ah1, bh, a); a = MFMA(ah1, bl, a); a = MFMA(al1, bh, a);
      acc[t] = a;
    }
    __syncthreads();
    #pragma unroll
    for (int t = 0; t < 4; ++t) {
      ushort4 h4, l4;
      float x;
      x = acc[t][0]; h4.x = f2b(x); l4.x = f2b(x - b2f(h4.x));
      x = acc[t][1]; h4.y = f2b(x); l4.y = f2b(x - b2f(h4.y));
      x = acc[t][2]; h4.z = f2b(x); l4.z = f2b(x - b2f(h4.z));
      x = acc[t][3]; h4.w = f2b(x); l4.w = f2b(x - b2f(h4.w));
      *(ushort4*)&buf0[(size_t)(16 * t + lrow) * S + m0 + 4 * lk] = h4;
      *(ushort4*)&buf1[(size_t)(16 * t + lrow) * S + m0 + 4 * lk] = l4;
    }
  }
  __syncthreads();

  // A3 = A @ A2 -> rows into buf0
  {
    f32x4 acc[4];
    #pragma unroll
    for (int t = 0; t < 4; ++t) {
      f32x4 a = {0.f, 0.f, 0.f, 0.f};
      bf16x8 bh = LD8(buf0, 16 * t + lrow, 8 * lk);
      bf16x8 bl = LD8(buf1, 16 * t + lrow, 8 * lk);
      a = MFMA(ah0, bh, a); a = MFMA(ah0, bl, a); a = MFMA(al0, bh, a);
      bh = LD8(buf0, 16 * t + lrow, 32 + 8 * lk);
      bl = LD8(buf1, 16 * t + lrow, 32 + 8 * lk);
      a = MFMA(ah1, bh, a); a = MFMA(ah1, bl, a); a = MFMA(al1, bh, a);
      acc[t] = a;
    }
    __syncthreads();
    #pragma unroll
    for (int t = 0; t < 4; ++t)
      #pragma unroll
      for (int r = 0; r < 4; ++r)
        buf0[(size_t)(m0 + 4 * lk + r) * S + 16 * t + lrow] = f2b(acc[t][r]);
  }
  __syncthreads();

  // coalesced store: a3g[b] = 64x64 bf16 row-major (8 KB)
  int4* dst = (int4*)(a3g + (size_t)b * (L * L));
  #pragma unroll
  for (int q = 0; q < 2; ++q) {
    int id = tid + 256 * q;
    int r = id >> 3, c8 = (id & 7) << 3;
    dst[id] = *(const int4*)&buf0[(size_t)r * S + c8];
  }
}

// ---------------------------------------------------------------------------
// Launch 2: [0,130) t0bf = E1 @ T^T (bf16, 2-buf)  |  [130,2178) A^3
// (t0bf tiles first so they don't tail the launch)
// ---------------------------------------------------------------------------
__global__ __launch_bounds__(256, 8) void k_pre2(const int* __restrict__ labels,
                                                 const unsigned char* __restrict__ adj8,
                                                 ushort* __restrict__ a3g,
                                                 const float* __restrict__ E1,
                                                 const float* __restrict__ T,
                                                 ushort* __restrict__ t0bf) {
  __shared__ __align__(16) ushort arena[2 * L * S];   // 18.4 KB
  __shared__ int   lab[L];
  __shared__ float ps[4][L];
  __shared__ float dv[L];
  int bid = blockIdx.x;
  if (bid < 130) {
    gemm2_body(arena, E1, T, t0bf, NN, bid % 26, bid / 26);
  } else {
    a3_body(arena, lab, ps, dv, labels, adj8, a3g, bid - 130);
  }
}

// ---------------------------------------------------------------------------
// Launch 3: out tiles. grid 8192: b = bid>>2, e-chunk c = bid&3.
// Stage A3[b] + Tt chunk, 1 barrier, MFMA, plain f32x4 stores (L2 combines
// the 1200B-stride partial lines; nontemporal here = RMW disaster, R11).
// ---------------------------------------------------------------------------
__global__ __launch_bounds__(256, 7) void k_out(const int* __restrict__ labels,
                                                const ushort* __restrict__ a3g,
                                                const ushort* __restrict__ t0bf,
                                                float* __restrict__ out) {
  __shared__ __align__(16) ushort A3L[L * S];    // 9216 B
  __shared__ __align__(16) ushort Tt[80 * S];    // 11520 B
  int bid = blockIdx.x;
  int b = bid >> 2, c = bid & 3;
  int tid = threadIdx.x, j = tid & 63, g = tid >> 6;
  int labj = labels[(size_t)b * L + j];

  // stage A3 rows (coalesced int4)
  const int4* a3p = (const int4*)(a3g + (size_t)b * (L * L));
  #pragma unroll
  for (int q = 0; q < 2; ++q) {
    int id = tid + 256 * q;
    int r = id >> 3, c8 = (id & 7) << 3;
    *(int4*)&A3L[(size_t)r * S + c8] = a3p[id];
  }
  // stage Tt[e_local][j] = t0bf[lab[j]][80c + e_local]
  int base = 80 * c;
  int rows80 = (c == 3) ? 64 : 80;
  const ushort* trow = t0bf + (size_t)labj * TSTR + base;
  for (int e = 8 * g; e < rows80; e += 32) {
    union { int4 v; ushort u[8]; } uu;
    uu.v = *(const int4*)(trow + e);
    #pragma unroll
    for (int q = 0; q < 8; ++q) Tt[(size_t)(e + q) * S + j] = uu.u[q];
  }
  __syncthreads();

  int lane = tid & 63, w = tid >> 6;
  int lrow = lane & 15, lk = lane >> 4;
  int m0 = 16 * w;
  bf16x8 fb0 = LD8(A3L, m0 + lrow, 8 * lk);
  bf16x8 fb1 = LD8(A3L, m0 + lrow, 32 + 8 * lk);
  float* orow = out + ((size_t)b * L + m0 + lrow) * EMB;

  int nt = (c == 3) ? 4 : 5;
  for (int t = 0; t < nt; ++t) {
    bf16x8 a0 = LD8(Tt, 16 * t + lrow, 8 * lk);
    bf16x8 a1 = LD8(Tt, 16 * t + lrow, 32 + 8 * lk);
    f32x4 o = {0.f, 0.f, 0.f, 0.f};
    o = MFMA(a0, fb0, o);
    o = MFMA(a1, fb1, o);
    int e0 = base + 16 * t + 4 * lk;
    if (e0 < EMB) *(f32x4*)&orow[e0] = o;
  }
}

// ---------------------------------------------------------------------------
extern "C" void kernel_launch(void* const* d_in, const int* in_sizes, int n_in,
                              void* d_out, int out_size, void* d_ws, size_t ws_size,
                              hipStream_t stream) {
  (void)in_sizes; (void)n_in; (void)out_size; (void)ws_size;
  const int*   labels = (const int*)d_in[0];
  const float* in_adj = (const float*)d_in[1];
  const float* emb    = (const float*)d_in[2];
  const float* lw     = (const float*)d_in[3];
  float* out = (float*)d_out;

  char* base = (char*)d_ws;
  unsigned char* adj8 = (unsigned char*)base;              // 2,563,201 B
  float*  T    = (float*)(base + 2563216);                 // 300x304 f32
  float*  E1   = (float*)(base + 2928016);                 // 1601x304 f32
  ushort* t0bf = (ushort*)(base + 4874832);                // 1601x304 bf16
  ushort* a3g  = (ushort*)(base + 5848240);                // 2048x64x64 bf16

  k_pre1<<<1179, 256, 0, stream>>>(in_adj, adj8, emb, lw, E1, T);
  k_pre2<<<2178, 256, 0, stream>>>(labels, adj8, a3g, E1, T, t0bf);
  k_out <<<4 * NB, 256, 0, stream>>>(labels, a3g, t0bf, out);
}

// Round 13
// 100.772 us; speedup vs baseline: 1.7167x; 1.0111x over previous
//
#include <hip/hip_runtime.h>

#define NN   1601
#define EMB  300
#define NB   2048
#define L    64
#define TSTR 304   // t0bf / T / E1 row stride (elements)
#define S    72    // LDS matrix stride (u16) -> 144B rows, 16B-aligned frags

typedef __attribute__((ext_vector_type(8))) short bf16x8;
typedef __attribute__((ext_vector_type(4))) float f32x4;

static __device__ __forceinline__ ushort f2b(float x) {
  union { float f; unsigned u; } c; c.f = x;
  unsigned u = c.u;
  return (ushort)((u + 0x7FFFu + ((u >> 16) & 1u)) >> 16);   // RNE
}
static __device__ __forceinline__ float b2f(ushort h) {
  union { unsigned u; float f; } c; c.u = ((unsigned)h) << 16; return c.f;
}

#define LD8(p, r, c) (*(const bf16x8*)&(p)[(size_t)(r) * S + (c)])
#define MFMA(a, bm, acc) __builtin_amdgcn_mfma_f32_16x16x32_bf16((a), (bm), (acc), 0, 0, 0)

// ---------------------------------------------------------------------------
// 4-buffer GEMM body (k_pre1 only): C = A@B^T (BT=1) or A@B (BT=0),
// hi/lo bf16 3-term MFMA (~f32). One 64x64 tile per call.
// ---------------------------------------------------------------------------
template <int BT, int BF16OUT>
__device__ __forceinline__ void gemm_body(ushort* arena,
                                          const float* __restrict__ A,
                                          const float* __restrict__ B,
                                          void* __restrict__ Cout,
                                          int M, int AS, int BS, int KG,
                                          int mb, int nb) {
  ushort* Ahi = arena;
  ushort* Alo = arena + L * S;
  ushort* Bhi = arena + 2 * L * S;
  ushort* Blo = arena + 3 * L * S;
  int tid = threadIdx.x;
  int lane = tid & 63, w = tid >> 6;
  int lrow = lane & 15, lk = lane >> 4;

  f32x4 acc[4];
  #pragma unroll
  for (int t = 0; t < 4; ++t) acc[t] = (f32x4){0.f, 0.f, 0.f, 0.f};

  for (int kc = 0; kc < 5; ++kc) {
    int k0 = 64 * kc;
    for (int idx = tid; idx < 64 * 16; idx += 256) {
      int r = idx >> 4, c4 = (idx & 15) * 4;
      int m = mb * 64 + r, k = k0 + c4;
      float4 v = make_float4(0.f, 0.f, 0.f, 0.f);
      if (m < M && k < KG) v = *(const float4*)&A[(size_t)m * AS + k];
      ushort4 h4, l4;
      h4.x = f2b(v.x); l4.x = f2b(v.x - b2f(h4.x));
      h4.y = f2b(v.y); l4.y = f2b(v.y - b2f(h4.y));
      h4.z = f2b(v.z); l4.z = f2b(v.z - b2f(h4.z));
      h4.w = f2b(v.w); l4.w = f2b(v.w - b2f(h4.w));
      *(ushort4*)&Ahi[r * S + c4] = h4;
      *(ushort4*)&Alo[r * S + c4] = l4;
    }
    for (int idx = tid; idx < 64 * 16; idx += 256) {
      int r = idx >> 4, c4 = (idx & 15) * 4;
      if (BT) {
        int n = nb * 64 + r, k = k0 + c4;
        float4 v = make_float4(0.f, 0.f, 0.f, 0.f);
        if (n < 300 && k < 300) v = *(const float4*)&B[(size_t)n * BS + k];
        ushort4 h4, l4;
        h4.x = f2b(v.x); l4.x = f2b(v.x - b2f(h4.x));
        h4.y = f2b(v.y); l4.y = f2b(v.y - b2f(h4.y));
        h4.z = f2b(v.z); l4.z = f2b(v.z - b2f(h4.z));
        h4.w = f2b(v.w); l4.w = f2b(v.w - b2f(h4.w));
        *(ushort4*)&Bhi[r * S + c4] = h4;
        *(ushort4*)&Blo[r * S + c4] = l4;
      } else {
        int k = k0 + r, n = nb * 64 + c4;
        float4 v = make_float4(0.f, 0.f, 0.f, 0.f);
        if (k < 300 && n < 300) v = *(const float4*)&B[(size_t)k * BS + n];
        #pragma unroll
        for (int q = 0; q < 4; ++q) {
          float xq = (q == 0) ? v.x : (q == 1) ? v.y : (q == 2) ? v.z : v.w;
          ushort hi = f2b(xq);
          Bhi[(size_t)(c4 + q) * S + r] = hi;
          Blo[(size_t)(c4 + q) * S + r] = f2b(xq - b2f(hi));
        }
      }
    }
    __syncthreads();
    #pragma unroll
    for (int ks = 0; ks < 2; ++ks) {
      bf16x8 ah = LD8(Ahi, 16 * w + lrow, 32 * ks + 8 * lk);
      bf16x8 al = LD8(Alo, 16 * w + lrow, 32 * ks + 8 * lk);
      #pragma unroll
      for (int t = 0; t < 4; ++t) {
        bf16x8 bh = LD8(Bhi, 16 * t + lrow, 32 * ks + 8 * lk);
        bf16x8 bl = LD8(Blo, 16 * t + lrow, 32 * ks + 8 * lk);
        acc[t] = MFMA(ah, bh, acc[t]);
        acc[t] = MFMA(ah, bl, acc[t]);
        acc[t] = MFMA(al, bh, acc[t]);
      }
    }
    __syncthreads();
  }
  #pragma unroll
  for (int t = 0; t < 4; ++t) {
    int n = nb * 64 + 16 * t + lrow;
    int mbase = mb * 64 + 16 * w + 4 * lk;
    if (n < TSTR) {
      #pragma unroll
      for (int r = 0; r < 4; ++r) {
        int m = mbase + r;
        if (m < M) {
          if (BF16OUT) ((ushort*)Cout)[(size_t)m * TSTR + n] = f2b(acc[t][r]);
          else         ((float*)Cout)[(size_t)m * TSTR + n] = acc[t][r];
        }
      }
    }
  }
}

// ---------------------------------------------------------------------------
// 2-buffer GEMM body (k_pre2's t0bf = E1 @ T^T, bf16 out). Same arithmetic,
// A-frags pass through regs so only 2 LDS buffers are needed (4 bars/kc).
// ---------------------------------------------------------------------------
__device__ __forceinline__ void gemm2_body(ushort* arena,
                                           const float* __restrict__ A,
                                           const float* __restrict__ B,
                                           ushort* __restrict__ Cout,
                                           int M, int mb, int nb) {
  ushort* buf0 = arena;
  ushort* buf1 = arena + L * S;
  int tid = threadIdx.x;
  int lane = tid & 63, w = tid >> 6;
  int lrow = lane & 15, lk = lane >> 4;

  f32x4 acc[4];
  #pragma unroll
  for (int t = 0; t < 4; ++t) acc[t] = (f32x4){0.f, 0.f, 0.f, 0.f};

  for (int kc = 0; kc < 5; ++kc) {
    int k0 = 64 * kc;
    // stage A tile hi/lo
    for (int idx = tid; idx < 64 * 16; idx += 256) {
      int r = idx >> 4, c4 = (idx & 15) * 4;
      int m = mb * 64 + r, k = k0 + c4;
      float4 v = make_float4(0.f, 0.f, 0.f, 0.f);
      if (m < M && k < TSTR) v = *(const float4*)&A[(size_t)m * TSTR + k];
      ushort4 h4, l4;
      h4.x = f2b(v.x); l4.x = f2b(v.x - b2f(h4.x));
      h4.y = f2b(v.y); l4.y = f2b(v.y - b2f(h4.y));
      h4.z = f2b(v.z); l4.z = f2b(v.z - b2f(h4.z));
      h4.w = f2b(v.w); l4.w = f2b(v.w - b2f(h4.w));
      *(ushort4*)&buf0[r * S + c4] = h4;
      *(ushort4*)&buf1[r * S + c4] = l4;
    }
    __syncthreads();
    bf16x8 ah0 = LD8(buf0, 16 * w + lrow, 8 * lk);
    bf16x8 ah1 = LD8(buf0, 16 * w + lrow, 32 + 8 * lk);
    bf16x8 al0 = LD8(buf1, 16 * w + lrow, 8 * lk);
    bf16x8 al1 = LD8(buf1, 16 * w + lrow, 32 + 8 * lk);
    __syncthreads();
    // stage B tile hi/lo (B^T operand: frag[n][k] = B[n][k], B stride TSTR)
    for (int idx = tid; idx < 64 * 16; idx += 256) {
      int r = idx >> 4, c4 = (idx & 15) * 4;
      int n = nb * 64 + r, k = k0 + c4;
      float4 v = make_float4(0.f, 0.f, 0.f, 0.f);
      if (n < 300 && k < TSTR) v = *(const float4*)&B[(size_t)n * TSTR + k];
      ushort4 h4, l4;
      h4.x = f2b(v.x); l4.x = f2b(v.x - b2f(h4.x));
      h4.y = f2b(v.y); l4.y = f2b(v.y - b2f(h4.y));
      h4.z = f2b(v.z); l4.z = f2b(v.z - b2f(h4.z));
      h4.w = f2b(v.w); l4.w = f2b(v.w - b2f(h4.w));
      *(ushort4*)&buf0[r * S + c4] = h4;
      *(ushort4*)&buf1[r * S + c4] = l4;
    }
    __syncthreads();
    #pragma unroll
    for (int t = 0; t < 4; ++t) {
      bf16x8 bh = LD8(buf0, 16 * t + lrow, 8 * lk);
      bf16x8 bl = LD8(buf1, 16 * t + lrow, 8 * lk);
      acc[t] = MFMA(ah0, bh, acc[t]);
      acc[t] = MFMA(ah0, bl, acc[t]);
      acc[t] = MFMA(al0, bh, acc[t]);
      bh = LD8(buf0, 16 * t + lrow, 32 + 8 * lk);
      bl = LD8(buf1, 16 * t + lrow, 32 + 8 * lk);
      acc[t] = MFMA(ah1, bh, acc[t]);
      acc[t] = MFMA(ah1, bl, acc[t]);
      acc[t] = MFMA(al1, bh, acc[t]);
    }
    __syncthreads();
  }
  #pragma unroll
  for (int t = 0; t < 4; ++t) {
    int n = nb * 64 + 16 * t + lrow;
    int mbase = mb * 64 + 16 * w + 4 * lk;
    if (n < TSTR) {
      #pragma unroll
      for (int r = 0; r < 4; ++r) {
        int m = mbase + r;
        if (m < M) Cout[(size_t)m * TSTR + n] = f2b(acc[t][r]);
      }
    }
  }
}

// ---------------------------------------------------------------------------
// Launch 1: [0,25) T = W3@W2 | [25,155) E1 = emb@W1^T | [155,1179) u8 quant
// ---------------------------------------------------------------------------
__global__ __launch_bounds__(256, 4) void k_pre1(const float* __restrict__ in_adj,
                                                 unsigned char* __restrict__ adj8,
                                                 const float* __restrict__ emb,
                                                 const float* __restrict__ lw,
                                                 float* __restrict__ E1,
                                                 float* __restrict__ T) {
  __shared__ __align__(16) ushort arena[4 * L * S];
  const float* W1 = lw;
  const float* W2 = lw + (size_t)EMB * EMB;
  const float* W3 = lw + 2 * (size_t)EMB * EMB;
  int bid = blockIdx.x;
  if (bid < 25) {
    gemm_body<0, 0>(arena, W3, W2, T, 300, 300, 300, 300, bid / 5, bid % 5);
  } else if (bid < 155) {
    int rid = bid - 25;
    gemm_body<1, 0>(arena, emb, W1, E1, NN, 300, 300, 300, rid % 26, rid / 26);
  } else {
    int b2 = bid - 155;
    const int total = NN * NN;           // 2563201
    const int n4 = total >> 2;
    int i = b2 * 256 + threadIdx.x;
    for (int i4 = i; i4 < n4; i4 += 1024 * 256) {
      float4 v = *(const float4*)&in_adj[4 * i4];
      uchar4 q;
      q.x = (unsigned char)__float2int_rn(v.x * 255.f);
      q.y = (unsigned char)__float2int_rn(v.y * 255.f);
      q.z = (unsigned char)__float2int_rn(v.z * 255.f);
      q.w = (unsigned char)__float2int_rn(v.w * 255.f);
      *(uchar4*)&adj8[4 * i4] = q;
    }
    if (i == 0)
      adj8[total - 1] = (unsigned char)__float2int_rn(in_adj[total - 1] * 255.f);
  }
}

// ---------------------------------------------------------------------------
// A^3 body, 2-buffer LDS: A = norm(gather_u8 + I); A2 = A@A; A3 = A@A2,
// hi/lo 3-term MFMA. Writes A3 (64x64 bf16 rows) to a3g[b].
// ---------------------------------------------------------------------------
__device__ __forceinline__ void a3_body(ushort* arena, int* lab, float (*ps)[L],
                                        float* dv, const int* __restrict__ labels,
                                        const unsigned char* __restrict__ adj8,
                                        ushort* __restrict__ a3g, int b) {
  ushort* buf0 = arena;
  ushort* buf1 = arena + L * S;
  int tid = threadIdx.x, j = tid & 63, g = tid >> 6;
  if (tid < L) lab[tid] = labels[(size_t)b * L + tid];
  __syncthreads();
  int labj = lab[j];

  float raw[16];
  float cs = 0.f;
  #pragma unroll
  for (int q = 0; q < 16; ++q) {
    int i = g + 4 * q;
    float v = (float)adj8[(size_t)lab[i] * NN + labj];
    v += (i == j) ? 255.f : 0.f;
    raw[q] = v; cs += v;
  }
  ps[g][j] = cs;
  __syncthreads();
  if (tid < L) dv[tid] = 1.f / sqrtf(ps[0][tid] + ps[1][tid] + ps[2][tid] + ps[3][tid]);
  __syncthreads();

  // A rows (hi/lo) into buf0/buf1; keep scaled values in regs
  float dj = dv[j];
  #pragma unroll
  for (int q = 0; q < 16; ++q) {
    int i = g + 4 * q;
    float a = raw[q] * dv[i] * dj;
    raw[q] = a;
    ushort hi = f2b(a);
    buf0[(size_t)i * S + j] = hi;
    buf1[(size_t)i * S + j] = f2b(a - b2f(hi));
  }
  __syncthreads();

  int lane = tid & 63, w = tid >> 6;
  int lrow = lane & 15, lk = lane >> 4;
  int m0 = 16 * w;

  bf16x8 ah0 = LD8(buf0, m0 + lrow, 8 * lk);
  bf16x8 ah1 = LD8(buf0, m0 + lrow, 32 + 8 * lk);
  bf16x8 al0 = LD8(buf1, m0 + lrow, 8 * lk);
  bf16x8 al1 = LD8(buf1, m0 + lrow, 32 + 8 * lk);
  __syncthreads();

  // overwrite with A^T (hi/lo)
  #pragma unroll
  for (int q = 0; q < 16; ++q) {
    int i = g + 4 * q;
    float a = raw[q];
    ushort hi = f2b(a);
    buf0[(size_t)j * S + i] = hi;
    buf1[(size_t)j * S + i] = f2b(a - b2f(hi));
  }
  __syncthreads();

  // A2 = A @ A -> overwrite buf0/1 with A2^T
  {
    f32x4 acc[4];
    #pragma unroll
    for (int t = 0; t < 4; ++t) {
      f32x4 a = {0.f, 0.f, 0.f, 0.f};
      bf16x8 bh = LD8(buf0, 16 * t + lrow, 8 * lk);
      bf16x8 bl = LD8(buf1, 16 * t + lrow, 8 * lk);
      a = MFMA(ah0, bh, a); a = MFMA(ah0, bl, a); a = MFMA(al0, bh, a);
      bh = LD8(buf0, 16 * t + lrow, 32 + 8 * lk);
      bl = LD8(buf1, 16 * t + lrow, 32 + 8 * lk);
      a = MFMA(ah1, bh, a); a = MFMA(ah1, bl, a); a = MFMA(al1, bh, a);
      acc[t] = a;
    }
    __syncthreads();
    #pragma unroll
    for (int t = 0; t < 4; ++t) {
      ushort4 h4, l4;
      float x;
      x = acc[t][0]; h4.x = f2b(x); l4.x = f2b(x - b2f(h4.x));
      x = acc[t][1]; h4.y = f2b(x); l4.y = f2b(x - b2f(h4.y));
      x = acc[t][2]; h4.z = f2b(x); l4.z = f2b(x - b2f(h4.z));
      x = acc[t][3]; h4.w = f2b(x); l4.w = f2b(x - b2f(h4.w));
      *(ushort4*)&buf0[(size_t)(16 * t + lrow) * S + m0 + 4 * lk] = h4;
      *(ushort4*)&buf1[(size_t)(16 * t + lrow) * S + m0 + 4 * lk] = l4;
    }
  }
  __syncthreads();

  // A3 = A @ A2 -> rows into buf0
  {
    f32x4 acc[4];
    #pragma unroll
    for (int t = 0; t < 4; ++t) {
      f32x4 a = {0.f, 0.f, 0.f, 0.f};
      bf16x8 bh = LD8(buf0, 16 * t + lrow, 8 * lk);
      bf16x8 bl = LD8(buf1, 16 * t + lrow, 8 * lk);
      a = MFMA(ah0, bh, a); a = MFMA(ah0, bl, a); a = MFMA(al0, bh, a);
      bh = LD8(buf0, 16 * t + lrow, 32 + 8 * lk);
      bl = LD8(buf1, 16 * t + lrow, 32 + 8 * lk);
      a = MFMA(ah1, bh, a); a = MFMA(ah1, bl, a); a = MFMA(al1, bh, a);
      acc[t] = a;
    }
    __syncthreads();
    #pragma unroll
    for (int t = 0; t < 4; ++t)
      #pragma unroll
      for (int r = 0; r < 4; ++r)
        buf0[(size_t)(m0 + 4 * lk + r) * S + 16 * t + lrow] = f2b(acc[t][r]);
  }
  __syncthreads();

  // coalesced store: a3g[b] = 64x64 bf16 row-major (8 KB)
  int4* dst = (int4*)(a3g + (size_t)b * (L * L));
  #pragma unroll
  for (int q = 0; q < 2; ++q) {
    int id = tid + 256 * q;
    int r = id >> 3, c8 = (id & 7) << 3;
    dst[id] = *(const int4*)&buf0[(size_t)r * S + c8];
  }
}

// ---------------------------------------------------------------------------
// Launch 2: [0,130) t0bf = E1 @ T^T (bf16, 2-buf)  |  [130,2178) A^3
// (t0bf tiles first so they don't tail the launch)
// ---------------------------------------------------------------------------
__global__ __launch_bounds__(256, 8) void k_pre2(const int* __restrict__ labels,
                                                 const unsigned char* __restrict__ adj8,
                                                 ushort* __restrict__ a3g,
                                                 const float* __restrict__ E1,
                                                 const float* __restrict__ T,
                                                 ushort* __restrict__ t0bf) {
  __shared__ __align__(16) ushort arena[2 * L * S];   // 18.4 KB
  __shared__ int   lab[L];
  __shared__ float ps[4][L];
  __shared__ float dv[L];
  int bid = blockIdx.x;
  if (bid < 130) {
    gemm2_body(arena, E1, T, t0bf, NN, bid % 26, bid / 26);
  } else {
    a3_body(arena, lab, ps, dv, labels, adj8, a3g, bid - 130);
  }
}

// ---------------------------------------------------------------------------
// Launch 3: out tiles. grid 8192: b = bid>>2, e-chunk c = bid&3.
// MFMA accs held in regs; results staged through an LDS obuf (overlaying the
// dead A3L/Tt arena) so global stores are contiguous float4 runs per row
// (the direct D-layout store was a 16-rows x 64B scatter -> ~3 TB/s).
// ---------------------------------------------------------------------------
__global__ __launch_bounds__(256, 7) void k_out(const int* __restrict__ labels,
                                                const ushort* __restrict__ a3g,
                                                const ushort* __restrict__ t0bf,
                                                float* __restrict__ out) {
  __shared__ __align__(16) ushort arena[10752];  // max(A3L+Tt 20736B, obuf 21504B)
  ushort* A3L = arena;            // [64][S]  9216 B
  ushort* Tt  = arena + L * S;    // [80][S] 11520 B
  int bid = blockIdx.x;
  int b = bid >> 2, c = bid & 3;
  int tid = threadIdx.x, j = tid & 63, g = tid >> 6;
  int labj = labels[(size_t)b * L + j];

  // stage A3 rows (coalesced int4)
  const int4* a3p = (const int4*)(a3g + (size_t)b * (L * L));
  #pragma unroll
  for (int q = 0; q < 2; ++q) {
    int id = tid + 256 * q;
    int r = id >> 3, c8 = (id & 7) << 3;
    *(int4*)&A3L[(size_t)r * S + c8] = a3p[id];
  }
  // stage Tt[e_local][j] = t0bf[lab[j]][80c + e_local]
  int base = 80 * c;
  int rows80 = (c == 3) ? 64 : 80;
  const ushort* trow = t0bf + (size_t)labj * TSTR + base;
  for (int e = 8 * g; e < rows80; e += 32) {
    union { int4 v; ushort u[8]; } uu;
    uu.v = *(const int4*)(trow + e);
    #pragma unroll
    for (int q = 0; q < 8; ++q) Tt[(size_t)(e + q) * S + j] = uu.u[q];
  }
  __syncthreads();

  int lane = tid & 63, w = tid >> 6;
  int lrow = lane & 15, lk = lane >> 4;
  int m0 = 16 * w;
  bf16x8 fb0 = LD8(A3L, m0 + lrow, 8 * lk);
  bf16x8 fb1 = LD8(A3L, m0 + lrow, 32 + 8 * lk);

  int nt = (c == 3) ? 4 : 5;
  f32x4 oacc[5];
  #pragma unroll
  for (int t = 0; t < 5; ++t) {
    f32x4 o = {0.f, 0.f, 0.f, 0.f};
    if (t < nt) {
      bf16x8 a0 = LD8(Tt, 16 * t + lrow, 8 * lk);
      bf16x8 a1 = LD8(Tt, 16 * t + lrow, 32 + 8 * lk);
      o = MFMA(a0, fb0, o);
      o = MFMA(a1, fb1, o);
    }
    oacc[t] = o;
  }
  __syncthreads();   // all A3L/Tt reads done; arena becomes obuf

  // obuf[64][84] f32: lane holds out[m0+lrow][base+16t+4lk .. +3]
  float* obuf = (float*)arena;
  #pragma unroll
  for (int t = 0; t < 5; ++t)
    *(f32x4*)&obuf[(size_t)(m0 + lrow) * 84 + 16 * t + 4 * lk] = oacc[t];
  __syncthreads();

  // coalesced copy: consecutive lanes -> consecutive float4 within a row
  int f4s = (c == 3) ? 15 : 20;            // float4 per row (60 or 80 cols)
  float* gbase = out + (size_t)b * L * EMB + base;
  for (int idx = tid; idx < 64 * f4s; idx += 256) {
    int r = idx / f4s, q = idx - r * f4s;
    *(f32x4*)&gbase[(size_t)r * EMB + 4 * q] =
        *(const f32x4*)&obuf[(size_t)r * 84 + 4 * q];
  }
}

// ---------------------------------------------------------------------------
extern "C" void kernel_launch(void* const* d_in, const int* in_sizes, int n_in,
                              void* d_out, int out_size, void* d_ws, size_t ws_size,
                              hipStream_t stream) {
  (void)in_sizes; (void)n_in; (void)out_size; (void)ws_size;
  const int*   labels = (const int*)d_in[0];
  const float* in_adj = (const float*)d_in[1];
  const float* emb    = (const float*)d_in[2];
  const float* lw     = (const float*)d_in[3];
  float* out = (float*)d_out;

  char* base = (char*)d_ws;
  unsigned char* adj8 = (unsigned char*)base;              // 2,563,201 B
  float*  T    = (float*)(base + 2563216);                 // 300x304 f32
  float*  E1   = (float*)(base + 2928016);                 // 1601x304 f32
  ushort* t0bf = (ushort*)(base + 4874832);                // 1601x304 bf16
  ushort* a3g  = (ushort*)(base + 5848240);                // 2048x64x64 bf16

  k_pre1<<<1179, 256, 0, stream>>>(in_adj, adj8, emb, lw, E1, T);
  k_pre2<<<2178, 256, 0, stream>>>(labels, adj8, a3g, E1, T, t0bf);
  k_out <<<4 * NB, 256, 0, stream>>>(labels, a3g, t0bf, out);
}

// Round 14
// 98.826 us; speedup vs baseline: 1.7505x; 1.0197x over previous
//
#include <hip/hip_runtime.h>

#define NN   1601
#define EMB  300
#define NB   2048
#define L    64
#define TSTR 304   // t0bf / T / E1 row stride (elements)
#define S    72    // LDS matrix stride (u16) -> 144B rows, 16B-aligned frags

typedef __attribute__((ext_vector_type(8))) short bf16x8;
typedef __attribute__((ext_vector_type(4))) float f32x4;

static __device__ __forceinline__ ushort f2b(float x) {
  union { float f; unsigned u; } c; c.f = x;
  unsigned u = c.u;
  return (ushort)((u + 0x7FFFu + ((u >> 16) & 1u)) >> 16);   // RNE
}
static __device__ __forceinline__ float b2f(ushort h) {
  union { unsigned u; float f; } c; c.u = ((unsigned)h) << 16; return c.f;
}

#define LD8(p, r, c) (*(const bf16x8*)&(p)[(size_t)(r) * S + (c)])
#define MFMA(a, bm, acc) __builtin_amdgcn_mfma_f32_16x16x32_bf16((a), (bm), (acc), 0, 0, 0)

// ---------------------------------------------------------------------------
// 4-buffer GEMM body (k_pre1 only): C = A@B^T (BT=1) or A@B (BT=0),
// hi/lo bf16 3-term MFMA (~f32). One 64x64 tile per call.
// ---------------------------------------------------------------------------
template <int BT, int BF16OUT>
__device__ __forceinline__ void gemm_body(ushort* arena,
                                          const float* __restrict__ A,
                                          const float* __restrict__ B,
                                          void* __restrict__ Cout,
                                          int M, int AS, int BS, int KG,
                                          int mb, int nb) {
  ushort* Ahi = arena;
  ushort* Alo = arena + L * S;
  ushort* Bhi = arena + 2 * L * S;
  ushort* Blo = arena + 3 * L * S;
  int tid = threadIdx.x;
  int lane = tid & 63, w = tid >> 6;
  int lrow = lane & 15, lk = lane >> 4;

  f32x4 acc[4];
  #pragma unroll
  for (int t = 0; t < 4; ++t) acc[t] = (f32x4){0.f, 0.f, 0.f, 0.f};

  for (int kc = 0; kc < 5; ++kc) {
    int k0 = 64 * kc;
    for (int idx = tid; idx < 64 * 16; idx += 256) {
      int r = idx >> 4, c4 = (idx & 15) * 4;
      int m = mb * 64 + r, k = k0 + c4;
      float4 v = make_float4(0.f, 0.f, 0.f, 0.f);
      if (m < M && k < KG) v = *(const float4*)&A[(size_t)m * AS + k];
      ushort4 h4, l4;
      h4.x = f2b(v.x); l4.x = f2b(v.x - b2f(h4.x));
      h4.y = f2b(v.y); l4.y = f2b(v.y - b2f(h4.y));
      h4.z = f2b(v.z); l4.z = f2b(v.z - b2f(h4.z));
      h4.w = f2b(v.w); l4.w = f2b(v.w - b2f(h4.w));
      *(ushort4*)&Ahi[r * S + c4] = h4;
      *(ushort4*)&Alo[r * S + c4] = l4;
    }
    for (int idx = tid; idx < 64 * 16; idx += 256) {
      int r = idx >> 4, c4 = (idx & 15) * 4;
      if (BT) {
        int n = nb * 64 + r, k = k0 + c4;
        float4 v = make_float4(0.f, 0.f, 0.f, 0.f);
        if (n < 300 && k < 300) v = *(const float4*)&B[(size_t)n * BS + k];
        ushort4 h4, l4;
        h4.x = f2b(v.x); l4.x = f2b(v.x - b2f(h4.x));
        h4.y = f2b(v.y); l4.y = f2b(v.y - b2f(h4.y));
        h4.z = f2b(v.z); l4.z = f2b(v.z - b2f(h4.z));
        h4.w = f2b(v.w); l4.w = f2b(v.w - b2f(h4.w));
        *(ushort4*)&Bhi[r * S + c4] = h4;
        *(ushort4*)&Blo[r * S + c4] = l4;
      } else {
        int k = k0 + r, n = nb * 64 + c4;
        float4 v = make_float4(0.f, 0.f, 0.f, 0.f);
        if (k < 300 && n < 300) v = *(const float4*)&B[(size_t)k * BS + n];
        #pragma unroll
        for (int q = 0; q < 4; ++q) {
          float xq = (q == 0) ? v.x : (q == 1) ? v.y : (q == 2) ? v.z : v.w;
          ushort hi = f2b(xq);
          Bhi[(size_t)(c4 + q) * S + r] = hi;
          Blo[(size_t)(c4 + q) * S + r] = f2b(xq - b2f(hi));
        }
      }
    }
    __syncthreads();
    #pragma unroll
    for (int ks = 0; ks < 2; ++ks) {
      bf16x8 ah = LD8(Ahi, 16 * w + lrow, 32 * ks + 8 * lk);
      bf16x8 al = LD8(Alo, 16 * w + lrow, 32 * ks + 8 * lk);
      #pragma unroll
      for (int t = 0; t < 4; ++t) {
        bf16x8 bh = LD8(Bhi, 16 * t + lrow, 32 * ks + 8 * lk);
        bf16x8 bl = LD8(Blo, 16 * t + lrow, 32 * ks + 8 * lk);
        acc[t] = MFMA(ah, bh, acc[t]);
        acc[t] = MFMA(ah, bl, acc[t]);
        acc[t] = MFMA(al, bh, acc[t]);
      }
    }
    __syncthreads();
  }
  #pragma unroll
  for (int t = 0; t < 4; ++t) {
    int n = nb * 64 + 16 * t + lrow;
    int mbase = mb * 64 + 16 * w + 4 * lk;
    if (n < TSTR) {
      #pragma unroll
      for (int r = 0; r < 4; ++r) {
        int m = mbase + r;
        if (m < M) {
          if (BF16OUT) ((ushort*)Cout)[(size_t)m * TSTR + n] = f2b(acc[t][r]);
          else         ((float*)Cout)[(size_t)m * TSTR + n] = acc[t][r];
        }
      }
    }
  }
}

// ---------------------------------------------------------------------------
// 2-buffer GEMM body (k_pre2's t0bf = E1 @ T^T, bf16 out). Same arithmetic,
// A-frags pass through regs so only 2 LDS buffers are needed (4 bars/kc).
// ---------------------------------------------------------------------------
__device__ __forceinline__ void gemm2_body(ushort* arena,
                                           const float* __restrict__ A,
                                           const float* __restrict__ B,
                                           ushort* __restrict__ Cout,
                                           int M, int mb, int nb) {
  ushort* buf0 = arena;
  ushort* buf1 = arena + L * S;
  int tid = threadIdx.x;
  int lane = tid & 63, w = tid >> 6;
  int lrow = lane & 15, lk = lane >> 4;

  f32x4 acc[4];
  #pragma unroll
  for (int t = 0; t < 4; ++t) acc[t] = (f32x4){0.f, 0.f, 0.f, 0.f};

  for (int kc = 0; kc < 5; ++kc) {
    int k0 = 64 * kc;
    // stage A tile hi/lo
    for (int idx = tid; idx < 64 * 16; idx += 256) {
      int r = idx >> 4, c4 = (idx & 15) * 4;
      int m = mb * 64 + r, k = k0 + c4;
      float4 v = make_float4(0.f, 0.f, 0.f, 0.f);
      if (m < M && k < TSTR) v = *(const float4*)&A[(size_t)m * TSTR + k];
      ushort4 h4, l4;
      h4.x = f2b(v.x); l4.x = f2b(v.x - b2f(h4.x));
      h4.y = f2b(v.y); l4.y = f2b(v.y - b2f(h4.y));
      h4.z = f2b(v.z); l4.z = f2b(v.z - b2f(h4.z));
      h4.w = f2b(v.w); l4.w = f2b(v.w - b2f(h4.w));
      *(ushort4*)&buf0[r * S + c4] = h4;
      *(ushort4*)&buf1[r * S + c4] = l4;
    }
    __syncthreads();
    bf16x8 ah0 = LD8(buf0, 16 * w + lrow, 8 * lk);
    bf16x8 ah1 = LD8(buf0, 16 * w + lrow, 32 + 8 * lk);
    bf16x8 al0 = LD8(buf1, 16 * w + lrow, 8 * lk);
    bf16x8 al1 = LD8(buf1, 16 * w + lrow, 32 + 8 * lk);
    __syncthreads();
    // stage B tile hi/lo (B^T operand: frag[n][k] = B[n][k], B stride TSTR)
    for (int idx = tid; idx < 64 * 16; idx += 256) {
      int r = idx >> 4, c4 = (idx & 15) * 4;
      int n = nb * 64 + r, k = k0 + c4;
      float4 v = make_float4(0.f, 0.f, 0.f, 0.f);
      if (n < 300 && k < TSTR) v = *(const float4*)&B[(size_t)n * TSTR + k];
      ushort4 h4, l4;
      h4.x = f2b(v.x); l4.x = f2b(v.x - b2f(h4.x));
      h4.y = f2b(v.y); l4.y = f2b(v.y - b2f(h4.y));
      h4.z = f2b(v.z); l4.z = f2b(v.z - b2f(h4.z));
      h4.w = f2b(v.w); l4.w = f2b(v.w - b2f(h4.w));
      *(ushort4*)&buf0[r * S + c4] = h4;
      *(ushort4*)&buf1[r * S + c4] = l4;
    }
    __syncthreads();
    #pragma unroll
    for (int t = 0; t < 4; ++t) {
      bf16x8 bh = LD8(buf0, 16 * t + lrow, 8 * lk);
      bf16x8 bl = LD8(buf1, 16 * t + lrow, 8 * lk);
      acc[t] = MFMA(ah0, bh, acc[t]);
      acc[t] = MFMA(ah0, bl, acc[t]);
      acc[t] = MFMA(al0, bh, acc[t]);
      bh = LD8(buf0, 16 * t + lrow, 32 + 8 * lk);
      bl = LD8(buf1, 16 * t + lrow, 32 + 8 * lk);
      acc[t] = MFMA(ah1, bh, acc[t]);
      acc[t] = MFMA(ah1, bl, acc[t]);
      acc[t] = MFMA(al1, bh, acc[t]);
    }
    __syncthreads();
  }
  #pragma unroll
  for (int t = 0; t < 4; ++t) {
    int n = nb * 64 + 16 * t + lrow;
    int mbase = mb * 64 + 16 * w + 4 * lk;
    if (n < TSTR) {
      #pragma unroll
      for (int r = 0; r < 4; ++r) {
        int m = mbase + r;
        if (m < M) Cout[(size_t)m * TSTR + n] = f2b(acc[t][r]);
      }
    }
  }
}

// ---------------------------------------------------------------------------
// Launch 1: [0,25) T = W3@W2 | [25,155) E1 = emb@W1^T | [155,1179) u8 quant
// ---------------------------------------------------------------------------
__global__ __launch_bounds__(256, 4) void k_pre1(const float* __restrict__ in_adj,
                                                 unsigned char* __restrict__ adj8,
                                                 const float* __restrict__ emb,
                                                 const float* __restrict__ lw,
                                                 float* __restrict__ E1,
                                                 float* __restrict__ T) {
  __shared__ __align__(16) ushort arena[4 * L * S];
  const float* W1 = lw;
  const float* W2 = lw + (size_t)EMB * EMB;
  const float* W3 = lw + 2 * (size_t)EMB * EMB;
  int bid = blockIdx.x;
  if (bid < 25) {
    gemm_body<0, 0>(arena, W3, W2, T, 300, 300, 300, 300, bid / 5, bid % 5);
  } else if (bid < 155) {
    int rid = bid - 25;
    gemm_body<1, 0>(arena, emb, W1, E1, NN, 300, 300, 300, rid % 26, rid / 26);
  } else {
    int b2 = bid - 155;
    const int total = NN * NN;           // 2563201
    const int n4 = total >> 2;
    int i = b2 * 256 + threadIdx.x;
    for (int i4 = i; i4 < n4; i4 += 1024 * 256) {
      float4 v = *(const float4*)&in_adj[4 * i4];
      uchar4 q;
      q.x = (unsigned char)__float2int_rn(v.x * 255.f);
      q.y = (unsigned char)__float2int_rn(v.y * 255.f);
      q.z = (unsigned char)__float2int_rn(v.z * 255.f);
      q.w = (unsigned char)__float2int_rn(v.w * 255.f);
      *(uchar4*)&adj8[4 * i4] = q;
    }
    if (i == 0)
      adj8[total - 1] = (unsigned char)__float2int_rn(in_adj[total - 1] * 255.f);
  }
}

// ---------------------------------------------------------------------------
// A^3 body, 2-buffer LDS: A = norm(gather_u8 + I); A2 = A@A; A3 = A@A2,
// hi/lo 3-term MFMA. Writes A3 (64x64 bf16 rows) to a3g[b].
// ---------------------------------------------------------------------------
__device__ __forceinline__ void a3_body(ushort* arena, int* lab, float (*ps)[L],
                                        float* dv, const int* __restrict__ labels,
                                        const unsigned char* __restrict__ adj8,
                                        ushort* __restrict__ a3g, int b) {
  ushort* buf0 = arena;
  ushort* buf1 = arena + L * S;
  int tid = threadIdx.x, j = tid & 63, g = tid >> 6;
  if (tid < L) lab[tid] = labels[(size_t)b * L + tid];
  __syncthreads();
  int labj = lab[j];

  float raw[16];
  float cs = 0.f;
  #pragma unroll
  for (int q = 0; q < 16; ++q) {
    int i = g + 4 * q;
    float v = (float)adj8[(size_t)lab[i] * NN + labj];
    v += (i == j) ? 255.f : 0.f;
    raw[q] = v; cs += v;
  }
  ps[g][j] = cs;
  __syncthreads();
  if (tid < L) dv[tid] = 1.f / sqrtf(ps[0][tid] + ps[1][tid] + ps[2][tid] + ps[3][tid]);
  __syncthreads();

  // A rows (hi/lo) into buf0/buf1; keep scaled values in regs
  float dj = dv[j];
  #pragma unroll
  for (int q = 0; q < 16; ++q) {
    int i = g + 4 * q;
    float a = raw[q] * dv[i] * dj;
    raw[q] = a;
    ushort hi = f2b(a);
    buf0[(size_t)i * S + j] = hi;
    buf1[(size_t)i * S + j] = f2b(a - b2f(hi));
  }
  __syncthreads();

  int lane = tid & 63, w = tid >> 6;
  int lrow = lane & 15, lk = lane >> 4;
  int m0 = 16 * w;

  bf16x8 ah0 = LD8(buf0, m0 + lrow, 8 * lk);
  bf16x8 ah1 = LD8(buf0, m0 + lrow, 32 + 8 * lk);
  bf16x8 al0 = LD8(buf1, m0 + lrow, 8 * lk);
  bf16x8 al1 = LD8(buf1, m0 + lrow, 32 + 8 * lk);
  __syncthreads();

  // overwrite with A^T (hi/lo)
  #pragma unroll
  for (int q = 0; q < 16; ++q) {
    int i = g + 4 * q;
    float a = raw[q];
    ushort hi = f2b(a);
    buf0[(size_t)j * S + i] = hi;
    buf1[(size_t)j * S + i] = f2b(a - b2f(hi));
  }
  __syncthreads();

  // A2 = A @ A -> overwrite buf0/1 with A2^T
  {
    f32x4 acc[4];
    #pragma unroll
    for (int t = 0; t < 4; ++t) {
      f32x4 a = {0.f, 0.f, 0.f, 0.f};
      bf16x8 bh = LD8(buf0, 16 * t + lrow, 8 * lk);
      bf16x8 bl = LD8(buf1, 16 * t + lrow, 8 * lk);
      a = MFMA(ah0, bh, a); a = MFMA(ah0, bl, a); a = MFMA(al0, bh, a);
      bh = LD8(buf0, 16 * t + lrow, 32 + 8 * lk);
      bl = LD8(buf1, 16 * t + lrow, 32 + 8 * lk);
      a = MFMA(ah1, bh, a); a = MFMA(ah1, bl, a); a = MFMA(al1, bh, a);
      acc[t] = a;
    }
    __syncthreads();
    #pragma unroll
    for (int t = 0; t < 4; ++t) {
      ushort4 h4, l4;
      float x;
      x = acc[t][0]; h4.x = f2b(x); l4.x = f2b(x - b2f(h4.x));
      x = acc[t][1]; h4.y = f2b(x); l4.y = f2b(x - b2f(h4.y));
      x = acc[t][2]; h4.z = f2b(x); l4.z = f2b(x - b2f(h4.z));
      x = acc[t][3]; h4.w = f2b(x); l4.w = f2b(x - b2f(h4.w));
      *(ushort4*)&buf0[(size_t)(16 * t + lrow) * S + m0 + 4 * lk] = h4;
      *(ushort4*)&buf1[(size_t)(16 * t + lrow) * S + m0 + 4 * lk] = l4;
    }
  }
  __syncthreads();

  // A3 = A @ A2 -> rows into buf0
  {
    f32x4 acc[4];
    #pragma unroll
    for (int t = 0; t < 4; ++t) {
      f32x4 a = {0.f, 0.f, 0.f, 0.f};
      bf16x8 bh = LD8(buf0, 16 * t + lrow, 8 * lk);
      bf16x8 bl = LD8(buf1, 16 * t + lrow, 8 * lk);
      a = MFMA(ah0, bh, a); a = MFMA(ah0, bl, a); a = MFMA(al0, bh, a);
      bh = LD8(buf0, 16 * t + lrow, 32 + 8 * lk);
      bl = LD8(buf1, 16 * t + lrow, 32 + 8 * lk);
      a = MFMA(ah1, bh, a); a = MFMA(ah1, bl, a); a = MFMA(al1, bh, a);
      acc[t] = a;
    }
    __syncthreads();
    #pragma unroll
    for (int t = 0; t < 4; ++t)
      #pragma unroll
      for (int r = 0; r < 4; ++r)
        buf0[(size_t)(m0 + 4 * lk + r) * S + 16 * t + lrow] = f2b(acc[t][r]);
  }
  __syncthreads();

  // coalesced store: a3g[b] = 64x64 bf16 row-major (8 KB)
  int4* dst = (int4*)(a3g + (size_t)b * (L * L));
  #pragma unroll
  for (int q = 0; q < 2; ++q) {
    int id = tid + 256 * q;
    int r = id >> 3, c8 = (id & 7) << 3;
    dst[id] = *(const int4*)&buf0[(size_t)r * S + c8];
  }
}

// ---------------------------------------------------------------------------
// Launch 2: [0,130) t0bf = E1 @ T^T (bf16, 2-buf)  |  [130,2178) A^3
// (t0bf tiles first so they don't tail the launch)
// ---------------------------------------------------------------------------
__global__ __launch_bounds__(256, 8) void k_pre2(const int* __restrict__ labels,
                                                 const unsigned char* __restrict__ adj8,
                                                 ushort* __restrict__ a3g,
                                                 const float* __restrict__ E1,
                                                 const float* __restrict__ T,
                                                 ushort* __restrict__ t0bf) {
  __shared__ __align__(16) ushort arena[2 * L * S];   // 18.4 KB
  __shared__ int   lab[L];
  __shared__ float ps[4][L];
  __shared__ float dv[L];
  int bid = blockIdx.x;
  if (bid < 130) {
    gemm2_body(arena, E1, T, t0bf, NN, bid % 26, bid / 26);
  } else {
    a3_body(arena, lab, ps, dv, labels, adj8, a3g, bid - 130);
  }
}

// ---------------------------------------------------------------------------
// Launch 3: out tiles. grid 8192: b = bid>>2, e-chunk c = bid&3.
// A3 fragments read DIRECTLY from global (L2-resident, 16B-aligned) -- no
// A3L stage, no extra barrier; LDS = Tt only (11.5 KB -> 8 blocks/CU).
// ---------------------------------------------------------------------------
__global__ __launch_bounds__(256, 8) void k_out(const int* __restrict__ labels,
                                                const ushort* __restrict__ a3g,
                                                const ushort* __restrict__ t0bf,
                                                float* __restrict__ out) {
  __shared__ __align__(16) ushort Tt[80 * S];    // 11520 B
  int bid = blockIdx.x;
  int b = bid >> 2, c = bid & 3;
  int tid = threadIdx.x, j = tid & 63, g = tid >> 6;
  int labj = labels[(size_t)b * L + j];

  int lane = tid & 63, w = tid >> 6;
  int lrow = lane & 15, lk = lane >> 4;
  int m0 = 16 * w;

  // B-side A3 fragments straight from global (row stride 64 u16 = 128 B)
  const ushort* a3b = a3g + (size_t)b * (L * L) + (size_t)(m0 + lrow) * L;
  bf16x8 fb0 = *(const bf16x8*)&a3b[8 * lk];
  bf16x8 fb1 = *(const bf16x8*)&a3b[32 + 8 * lk];

  // stage Tt[e_local][j] = t0bf[lab[j]][80c + e_local]
  int base = 80 * c;
  int rows80 = (c == 3) ? 64 : 80;
  const ushort* trow = t0bf + (size_t)labj * TSTR + base;
  for (int e = 8 * g; e < rows80; e += 32) {
    union { int4 v; ushort u[8]; } uu;
    uu.v = *(const int4*)(trow + e);
    #pragma unroll
    for (int q = 0; q < 8; ++q) Tt[(size_t)(e + q) * S + j] = uu.u[q];
  }
  __syncthreads();

  float* orow = out + ((size_t)b * L + m0 + lrow) * EMB;
  int nt = (c == 3) ? 4 : 5;
  for (int t = 0; t < nt; ++t) {
    bf16x8 a0 = LD8(Tt, 16 * t + lrow, 8 * lk);
    bf16x8 a1 = LD8(Tt, 16 * t + lrow, 32 + 8 * lk);
    f32x4 o = {0.f, 0.f, 0.f, 0.f};
    o = MFMA(a0, fb0, o);
    o = MFMA(a1, fb1, o);
    int e0 = base + 16 * t + 4 * lk;
    if (e0 < EMB) *(f32x4*)&orow[e0] = o;
  }
}

// ---------------------------------------------------------------------------
extern "C" void kernel_launch(void* const* d_in, const int* in_sizes, int n_in,
                              void* d_out, int out_size, void* d_ws, size_t ws_size,
                              hipStream_t stream) {
  (void)in_sizes; (void)n_in; (void)out_size; (void)ws_size;
  const int*   labels = (const int*)d_in[0];
  const float* in_adj = (const float*)d_in[1];
  const float* emb    = (const float*)d_in[2];
  const float* lw     = (const float*)d_in[3];
  float* out = (float*)d_out;

  char* base = (char*)d_ws;
  unsigned char* adj8 = (unsigned char*)base;              // 2,563,201 B
  float*  T    = (float*)(base + 2563216);                 // 300x304 f32
  float*  E1   = (float*)(base + 2928016);                 // 1601x304 f32
  ushort* t0bf = (ushort*)(base + 4874832);                // 1601x304 bf16
  ushort* a3g  = (ushort*)(base + 5848240);                // 2048x64x64 bf16

  k_pre1<<<1179, 256, 0, stream>>>(in_adj, adj8, emb, lw, E1, T);
  k_pre2<<<2178, 256, 0, stream>>>(labels, adj8, a3g, E1, T, t0bf);
  k_out <<<4 * NB, 256, 0, stream>>>(labels, a3g, t0bf, out);
}

// Round 15
// 97.386 us; speedup vs baseline: 1.7763x; 1.0148x over previous
//
#include <hip/hip_runtime.h>

#define NN   1601
#define EMB  300
#define NB   2048
#define L    64
#define TSTR 304   // t0bf / T / E1 row stride (elements)
#define S    72    // LDS matrix stride (u16) -> 144B rows, 16B-aligned frags

typedef __attribute__((ext_vector_type(8))) short bf16x8;
typedef __attribute__((ext_vector_type(4))) float f32x4;

static __device__ __forceinline__ ushort f2b(float x) {
  union { float f; unsigned u; } c; c.f = x;
  unsigned u = c.u;
  return (ushort)((u + 0x7FFFu + ((u >> 16) & 1u)) >> 16);   // RNE
}
static __device__ __forceinline__ float b2f(ushort h) {
  union { unsigned u; float f; } c; c.u = ((unsigned)h) << 16; return c.f;
}

#define LD8(p, r, c) (*(const bf16x8*)&(p)[(size_t)(r) * S + (c)])
#define MFMA(a, bm, acc) __builtin_amdgcn_mfma_f32_16x16x32_bf16((a), (bm), (acc), 0, 0, 0)

// ---------------------------------------------------------------------------
// 4-buffer GEMM body (k_pre1 only): C = A@B^T (BT=1) or A@B (BT=0),
// hi/lo bf16 3-term MFMA (~f32). One 64x64 tile per call.
// ---------------------------------------------------------------------------
template <int BT, int BF16OUT>
__device__ __forceinline__ void gemm_body(ushort* arena,
                                          const float* __restrict__ A,
                                          const float* __restrict__ B,
                                          void* __restrict__ Cout,
                                          int M, int AS, int BS, int KG,
                                          int mb, int nb) {
  ushort* Ahi = arena;
  ushort* Alo = arena + L * S;
  ushort* Bhi = arena + 2 * L * S;
  ushort* Blo = arena + 3 * L * S;
  int tid = threadIdx.x;
  int lane = tid & 63, w = tid >> 6;
  int lrow = lane & 15, lk = lane >> 4;

  f32x4 acc[4];
  #pragma unroll
  for (int t = 0; t < 4; ++t) acc[t] = (f32x4){0.f, 0.f, 0.f, 0.f};

  for (int kc = 0; kc < 5; ++kc) {
    int k0 = 64 * kc;
    for (int idx = tid; idx < 64 * 16; idx += 256) {
      int r = idx >> 4, c4 = (idx & 15) * 4;
      int m = mb * 64 + r, k = k0 + c4;
      float4 v = make_float4(0.f, 0.f, 0.f, 0.f);
      if (m < M && k < KG) v = *(const float4*)&A[(size_t)m * AS + k];
      ushort4 h4, l4;
      h4.x = f2b(v.x); l4.x = f2b(v.x - b2f(h4.x));
      h4.y = f2b(v.y); l4.y = f2b(v.y - b2f(h4.y));
      h4.z = f2b(v.z); l4.z = f2b(v.z - b2f(h4.z));
      h4.w = f2b(v.w); l4.w = f2b(v.w - b2f(h4.w));
      *(ushort4*)&Ahi[r * S + c4] = h4;
      *(ushort4*)&Alo[r * S + c4] = l4;
    }
    for (int idx = tid; idx < 64 * 16; idx += 256) {
      int r = idx >> 4, c4 = (idx & 15) * 4;
      if (BT) {
        int n = nb * 64 + r, k = k0 + c4;
        float4 v = make_float4(0.f, 0.f, 0.f, 0.f);
        if (n < 300 && k < 300) v = *(const float4*)&B[(size_t)n * BS + k];
        ushort4 h4, l4;
        h4.x = f2b(v.x); l4.x = f2b(v.x - b2f(h4.x));
        h4.y = f2b(v.y); l4.y = f2b(v.y - b2f(h4.y));
        h4.z = f2b(v.z); l4.z = f2b(v.z - b2f(h4.z));
        h4.w = f2b(v.w); l4.w = f2b(v.w - b2f(h4.w));
        *(ushort4*)&Bhi[r * S + c4] = h4;
        *(ushort4*)&Blo[r * S + c4] = l4;
      } else {
        int k = k0 + r, n = nb * 64 + c4;
        float4 v = make_float4(0.f, 0.f, 0.f, 0.f);
        if (k < 300 && n < 300) v = *(const float4*)&B[(size_t)k * BS + n];
        #pragma unroll
        for (int q = 0; q < 4; ++q) {
          float xq = (q == 0) ? v.x : (q == 1) ? v.y : (q == 2) ? v.z : v.w;
          ushort hi = f2b(xq);
          Bhi[(size_t)(c4 + q) * S + r] = hi;
          Blo[(size_t)(c4 + q) * S + r] = f2b(xq - b2f(hi));
        }
      }
    }
    __syncthreads();
    #pragma unroll
    for (int ks = 0; ks < 2; ++ks) {
      bf16x8 ah = LD8(Ahi, 16 * w + lrow, 32 * ks + 8 * lk);
      bf16x8 al = LD8(Alo, 16 * w + lrow, 32 * ks + 8 * lk);
      #pragma unroll
      for (int t = 0; t < 4; ++t) {
        bf16x8 bh = LD8(Bhi, 16 * t + lrow, 32 * ks + 8 * lk);
        bf16x8 bl = LD8(Blo, 16 * t + lrow, 32 * ks + 8 * lk);
        acc[t] = MFMA(ah, bh, acc[t]);
        acc[t] = MFMA(ah, bl, acc[t]);
        acc[t] = MFMA(al, bh, acc[t]);
      }
    }
    __syncthreads();
  }
  #pragma unroll
  for (int t = 0; t < 4; ++t) {
    int n = nb * 64 + 16 * t + lrow;
    int mbase = mb * 64 + 16 * w + 4 * lk;
    if (n < TSTR) {
      #pragma unroll
      for (int r = 0; r < 4; ++r) {
        int m = mbase + r;
        if (m < M) {
          if (BF16OUT) ((ushort*)Cout)[(size_t)m * TSTR + n] = f2b(acc[t][r]);
          else         ((float*)Cout)[(size_t)m * TSTR + n] = acc[t][r];
        }
      }
    }
  }
}

// ---------------------------------------------------------------------------
// 2-buffer GEMM body (k_pre2's t0bf = E1 @ T^T, bf16 out). Same arithmetic,
// A-frags pass through regs so only 2 LDS buffers are needed (4 bars/kc).
// ---------------------------------------------------------------------------
__device__ __forceinline__ void gemm2_body(ushort* arena,
                                           const float* __restrict__ A,
                                           const float* __restrict__ B,
                                           ushort* __restrict__ Cout,
                                           int M, int mb, int nb) {
  ushort* buf0 = arena;
  ushort* buf1 = arena + L * S;
  int tid = threadIdx.x;
  int lane = tid & 63, w = tid >> 6;
  int lrow = lane & 15, lk = lane >> 4;

  f32x4 acc[4];
  #pragma unroll
  for (int t = 0; t < 4; ++t) acc[t] = (f32x4){0.f, 0.f, 0.f, 0.f};

  for (int kc = 0; kc < 5; ++kc) {
    int k0 = 64 * kc;
    // stage A tile hi/lo
    for (int idx = tid; idx < 64 * 16; idx += 256) {
      int r = idx >> 4, c4 = (idx & 15) * 4;
      int m = mb * 64 + r, k = k0 + c4;
      float4 v = make_float4(0.f, 0.f, 0.f, 0.f);
      if (m < M && k < TSTR) v = *(const float4*)&A[(size_t)m * TSTR + k];
      ushort4 h4, l4;
      h4.x = f2b(v.x); l4.x = f2b(v.x - b2f(h4.x));
      h4.y = f2b(v.y); l4.y = f2b(v.y - b2f(h4.y));
      h4.z = f2b(v.z); l4.z = f2b(v.z - b2f(h4.z));
      h4.w = f2b(v.w); l4.w = f2b(v.w - b2f(h4.w));
      *(ushort4*)&buf0[r * S + c4] = h4;
      *(ushort4*)&buf1[r * S + c4] = l4;
    }
    __syncthreads();
    bf16x8 ah0 = LD8(buf0, 16 * w + lrow, 8 * lk);
    bf16x8 ah1 = LD8(buf0, 16 * w + lrow, 32 + 8 * lk);
    bf16x8 al0 = LD8(buf1, 16 * w + lrow, 8 * lk);
    bf16x8 al1 = LD8(buf1, 16 * w + lrow, 32 + 8 * lk);
    __syncthreads();
    // stage B tile hi/lo (B^T operand: frag[n][k] = B[n][k], B stride TSTR)
    for (int idx = tid; idx < 64 * 16; idx += 256) {
      int r = idx >> 4, c4 = (idx & 15) * 4;
      int n = nb * 64 + r, k = k0 + c4;
      float4 v = make_float4(0.f, 0.f, 0.f, 0.f);
      if (n < 300 && k < TSTR) v = *(const float4*)&B[(size_t)n * TSTR + k];
      ushort4 h4, l4;
      h4.x = f2b(v.x); l4.x = f2b(v.x - b2f(h4.x));
      h4.y = f2b(v.y); l4.y = f2b(v.y - b2f(h4.y));
      h4.z = f2b(v.z); l4.z = f2b(v.z - b2f(h4.z));
      h4.w = f2b(v.w); l4.w = f2b(v.w - b2f(h4.w));
      *(ushort4*)&buf0[r * S + c4] = h4;
      *(ushort4*)&buf1[r * S + c4] = l4;
    }
    __syncthreads();
    #pragma unroll
    for (int t = 0; t < 4; ++t) {
      bf16x8 bh = LD8(buf0, 16 * t + lrow, 8 * lk);
      bf16x8 bl = LD8(buf1, 16 * t + lrow, 8 * lk);
      acc[t] = MFMA(ah0, bh, acc[t]);
      acc[t] = MFMA(ah0, bl, acc[t]);
      acc[t] = MFMA(al0, bh, acc[t]);
      bh = LD8(buf0, 16 * t + lrow, 32 + 8 * lk);
      bl = LD8(buf1, 16 * t + lrow, 32 + 8 * lk);
      acc[t] = MFMA(ah1, bh, acc[t]);
      acc[t] = MFMA(ah1, bl, acc[t]);
      acc[t] = MFMA(al1, bh, acc[t]);
    }
    __syncthreads();
  }
  #pragma unroll
  for (int t = 0; t < 4; ++t) {
    int n = nb * 64 + 16 * t + lrow;
    int mbase = mb * 64 + 16 * w + 4 * lk;
    if (n < TSTR) {
      #pragma unroll
      for (int r = 0; r < 4; ++r) {
        int m = mbase + r;
        if (m < M) Cout[(size_t)m * TSTR + n] = f2b(acc[t][r]);
      }
    }
  }
}

// ---------------------------------------------------------------------------
// Launch 1: [0,25) T = W3@W2 | [25,155) E1 = emb@W1^T | [155,1179) u8 quant
// ---------------------------------------------------------------------------
__global__ __launch_bounds__(256, 4) void k_pre1(const float* __restrict__ in_adj,
                                                 unsigned char* __restrict__ adj8,
                                                 const float* __restrict__ emb,
                                                 const float* __restrict__ lw,
                                                 float* __restrict__ E1,
                                                 float* __restrict__ T) {
  __shared__ __align__(16) ushort arena[4 * L * S];
  const float* W1 = lw;
  const float* W2 = lw + (size_t)EMB * EMB;
  const float* W3 = lw + 2 * (size_t)EMB * EMB;
  int bid = blockIdx.x;
  if (bid < 25) {
    gemm_body<0, 0>(arena, W3, W2, T, 300, 300, 300, 300, bid / 5, bid % 5);
  } else if (bid < 155) {
    int rid = bid - 25;
    gemm_body<1, 0>(arena, emb, W1, E1, NN, 300, 300, 300, rid % 26, rid / 26);
  } else {
    int b2 = bid - 155;
    const int total = NN * NN;           // 2563201
    const int n4 = total >> 2;
    int i = b2 * 256 + threadIdx.x;
    for (int i4 = i; i4 < n4; i4 += 1024 * 256) {
      float4 v = *(const float4*)&in_adj[4 * i4];
      uchar4 q;
      q.x = (unsigned char)__float2int_rn(v.x * 255.f);
      q.y = (unsigned char)__float2int_rn(v.y * 255.f);
      q.z = (unsigned char)__float2int_rn(v.z * 255.f);
      q.w = (unsigned char)__float2int_rn(v.w * 255.f);
      *(uchar4*)&adj8[4 * i4] = q;
    }
    if (i == 0)
      adj8[total - 1] = (unsigned char)__float2int_rn(in_adj[total - 1] * 255.f);
  }
}

// ---------------------------------------------------------------------------
// A^3 body, 2-buffer LDS: A = norm(gather_u8 + I); A2 = A@A; A3 = A@A2,
// hi/lo 3-term MFMA. Writes A3 (64x64 bf16 rows) to a3g[b].
// ---------------------------------------------------------------------------
__device__ __forceinline__ void a3_body(ushort* arena, int* lab, float (*ps)[L],
                                        float* dv, const int* __restrict__ labels,
                                        const unsigned char* __restrict__ adj8,
                                        ushort* __restrict__ a3g, int b) {
  ushort* buf0 = arena;
  ushort* buf1 = arena + L * S;
  int tid = threadIdx.x, j = tid & 63, g = tid >> 6;
  if (tid < L) lab[tid] = labels[(size_t)b * L + tid];
  __syncthreads();
  int labj = lab[j];

  float raw[16];
  float cs = 0.f;
  #pragma unroll
  for (int q = 0; q < 16; ++q) {
    int i = g + 4 * q;
    float v = (float)adj8[(size_t)lab[i] * NN + labj];
    v += (i == j) ? 255.f : 0.f;
    raw[q] = v; cs += v;
  }
  ps[g][j] = cs;
  __syncthreads();
  if (tid < L) dv[tid] = 1.f / sqrtf(ps[0][tid] + ps[1][tid] + ps[2][tid] + ps[3][tid]);
  __syncthreads();

  // A rows (hi/lo) into buf0/buf1; keep scaled values in regs
  float dj = dv[j];
  #pragma unroll
  for (int q = 0; q < 16; ++q) {
    int i = g + 4 * q;
    float a = raw[q] * dv[i] * dj;
    raw[q] = a;
    ushort hi = f2b(a);
    buf0[(size_t)i * S + j] = hi;
    buf1[(size_t)i * S + j] = f2b(a - b2f(hi));
  }
  __syncthreads();

  int lane = tid & 63, w = tid >> 6;
  int lrow = lane & 15, lk = lane >> 4;
  int m0 = 16 * w;

  bf16x8 ah0 = LD8(buf0, m0 + lrow, 8 * lk);
  bf16x8 ah1 = LD8(buf0, m0 + lrow, 32 + 8 * lk);
  bf16x8 al0 = LD8(buf1, m0 + lrow, 8 * lk);
  bf16x8 al1 = LD8(buf1, m0 + lrow, 32 + 8 * lk);
  __syncthreads();

  // overwrite with A^T (hi/lo)
  #pragma unroll
  for (int q = 0; q < 16; ++q) {
    int i = g + 4 * q;
    float a = raw[q];
    ushort hi = f2b(a);
    buf0[(size_t)j * S + i] = hi;
    buf1[(size_t)j * S + i] = f2b(a - b2f(hi));
  }
  __syncthreads();

  // A2 = A @ A -> overwrite buf0/1 with A2^T
  {
    f32x4 acc[4];
    #pragma unroll
    for (int t = 0; t < 4; ++t) {
      f32x4 a = {0.f, 0.f, 0.f, 0.f};
      bf16x8 bh = LD8(buf0, 16 * t + lrow, 8 * lk);
      bf16x8 bl = LD8(buf1, 16 * t + lrow, 8 * lk);
      a = MFMA(ah0, bh, a); a = MFMA(ah0, bl, a); a = MFMA(al0, bh, a);
      bh = LD8(buf0, 16 * t + lrow, 32 + 8 * lk);
      bl = LD8(buf1, 16 * t + lrow, 32 + 8 * lk);
      a = MFMA(ah1, bh, a); a = MFMA(ah1, bl, a); a = MFMA(al1, bh, a);
      acc[t] = a;
    }
    __syncthreads();
    #pragma unroll
    for (int t = 0; t < 4; ++t) {
      ushort4 h4, l4;
      float x;
      x = acc[t][0]; h4.x = f2b(x); l4.x = f2b(x - b2f(h4.x));
      x = acc[t][1]; h4.y = f2b(x); l4.y = f2b(x - b2f(h4.y));
      x = acc[t][2]; h4.z = f2b(x); l4.z = f2b(x - b2f(h4.z));
      x = acc[t][3]; h4.w = f2b(x); l4.w = f2b(x - b2f(h4.w));
      *(ushort4*)&buf0[(size_t)(16 * t + lrow) * S + m0 + 4 * lk] = h4;
      *(ushort4*)&buf1[(size_t)(16 * t + lrow) * S + m0 + 4 * lk] = l4;
    }
  }
  __syncthreads();

  // A3 = A @ A2 -> rows into buf0
  {
    f32x4 acc[4];
    #pragma unroll
    for (int t = 0; t < 4; ++t) {
      f32x4 a = {0.f, 0.f, 0.f, 0.f};
      bf16x8 bh = LD8(buf0, 16 * t + lrow, 8 * lk);
      bf16x8 bl = LD8(buf1, 16 * t + lrow, 8 * lk);
      a = MFMA(ah0, bh, a); a = MFMA(ah0, bl, a); a = MFMA(al0, bh, a);
      bh = LD8(buf0, 16 * t + lrow, 32 + 8 * lk);
      bl = LD8(buf1, 16 * t + lrow, 32 + 8 * lk);
      a = MFMA(ah1, bh, a); a = MFMA(ah1, bl, a); a = MFMA(al1, bh, a);
      acc[t] = a;
    }
    __syncthreads();
    #pragma unroll
    for (int t = 0; t < 4; ++t)
      #pragma unroll
      for (int r = 0; r < 4; ++r)
        buf0[(size_t)(m0 + 4 * lk + r) * S + 16 * t + lrow] = f2b(acc[t][r]);
  }
  __syncthreads();

  // coalesced store: a3g[b] = 64x64 bf16 row-major (8 KB)
  int4* dst = (int4*)(a3g + (size_t)b * (L * L));
  #pragma unroll
  for (int q = 0; q < 2; ++q) {
    int id = tid + 256 * q;
    int r = id >> 3, c8 = (id & 7) << 3;
    dst[id] = *(const int4*)&buf0[(size_t)r * S + c8];
  }
}

// ---------------------------------------------------------------------------
// Launch 2: [0,130) t0bf = E1 @ T^T (bf16, 2-buf)  |  [130,2178) A^3
// (t0bf tiles first so they don't tail the launch)
// ---------------------------------------------------------------------------
__global__ __launch_bounds__(256, 8) void k_pre2(const int* __restrict__ labels,
                                                 const unsigned char* __restrict__ adj8,
                                                 ushort* __restrict__ a3g,
                                                 const float* __restrict__ E1,
                                                 const float* __restrict__ T,
                                                 ushort* __restrict__ t0bf) {
  __shared__ __align__(16) ushort arena[2 * L * S];   // 18.4 KB
  __shared__ int   lab[L];
  __shared__ float ps[4][L];
  __shared__ float dv[L];
  int bid = blockIdx.x;
  if (bid < 130) {
    gemm2_body(arena, E1, T, t0bf, NN, bid % 26, bid / 26);
  } else {
    a3_body(arena, lab, ps, dv, labels, adj8, a3g, bid - 130);
  }
}

// ---------------------------------------------------------------------------
// Launch 3: out tiles. grid 8192. XCD-aware decode: b = bid & 2047,
// c = bid >> 11 -> all 4 e-chunks of a batch land on the SAME XCD
// (bid % 8 == b % 8), so the mid-line chunk/row borders of the 1200B-stride
// output are merged in ONE L2 instead of RMW-split across two XCDs.
// ---------------------------------------------------------------------------
__global__ __launch_bounds__(256, 8) void k_out(const int* __restrict__ labels,
                                                const ushort* __restrict__ a3g,
                                                const ushort* __restrict__ t0bf,
                                                float* __restrict__ out) {
  __shared__ __align__(16) ushort Tt[80 * S];    // 11520 B
  int bid = blockIdx.x;
  int b = bid & 2047, c = bid >> 11;
  int tid = threadIdx.x, j = tid & 63, g = tid >> 6;
  int labj = labels[(size_t)b * L + j];

  int lane = tid & 63, w = tid >> 6;
  int lrow = lane & 15, lk = lane >> 4;
  int m0 = 16 * w;

  // B-side A3 fragments straight from global (row stride 64 u16 = 128 B)
  const ushort* a3b = a3g + (size_t)b * (L * L) + (size_t)(m0 + lrow) * L;
  bf16x8 fb0 = *(const bf16x8*)&a3b[8 * lk];
  bf16x8 fb1 = *(const bf16x8*)&a3b[32 + 8 * lk];

  // stage Tt[e_local][j] = t0bf[lab[j]][80c + e_local]
  int base = 80 * c;
  int rows80 = (c == 3) ? 64 : 80;
  const ushort* trow = t0bf + (size_t)labj * TSTR + base;
  for (int e = 8 * g; e < rows80; e += 32) {
    union { int4 v; ushort u[8]; } uu;
    uu.v = *(const int4*)(trow + e);
    #pragma unroll
    for (int q = 0; q < 8; ++q) Tt[(size_t)(e + q) * S + j] = uu.u[q];
  }
  __syncthreads();

  float* orow = out + ((size_t)b * L + m0 + lrow) * EMB;
  int nt = (c == 3) ? 4 : 5;
  for (int t = 0; t < nt; ++t) {
    bf16x8 a0 = LD8(Tt, 16 * t + lrow, 8 * lk);
    bf16x8 a1 = LD8(Tt, 16 * t + lrow, 32 + 8 * lk);
    f32x4 o = {0.f, 0.f, 0.f, 0.f};
    o = MFMA(a0, fb0, o);
    o = MFMA(a1, fb1, o);
    int e0 = base + 16 * t + 4 * lk;
    if (e0 < EMB) *(f32x4*)&orow[e0] = o;
  }
}

// ---------------------------------------------------------------------------
extern "C" void kernel_launch(void* const* d_in, const int* in_sizes, int n_in,
                              void* d_out, int out_size, void* d_ws, size_t ws_size,
                              hipStream_t stream) {
  (void)in_sizes; (void)n_in; (void)out_size; (void)ws_size;
  const int*   labels = (const int*)d_in[0];
  const float* in_adj = (const float*)d_in[1];
  const float* emb    = (const float*)d_in[2];
  const float* lw     = (const float*)d_in[3];
  float* out = (float*)d_out;

  char* base = (char*)d_ws;
  unsigned char* adj8 = (unsigned char*)base;              // 2,563,201 B
  float*  T    = (float*)(base + 2563216);                 // 300x304 f32
  float*  E1   = (float*)(base + 2928016);                 // 1601x304 f32
  ushort* t0bf = (ushort*)(base + 4874832);                // 1601x304 bf16
  ushort* a3g  = (ushort*)(base + 5848240);                // 2048x64x64 bf16

  k_pre1<<<1179, 256, 0, stream>>>(in_adj, adj8, emb, lw, E1, T);
  k_pre2<<<2178, 256, 0, stream>>>(labels, adj8, a3g, E1, T, t0bf);
  k_out <<<4 * NB, 256, 0, stream>>>(labels, a3g, t0bf, out);
}

// Round 16
// 92.217 us; speedup vs baseline: 1.8759x; 1.0561x over previous
//
#include <hip/hip_runtime.h>

#define NN   1601
#define EMB  300
#define NB   2048
#define L    64
#define TSTR 304   // t0bf / T / E1 row stride (elements)
#define S    72    // LDS matrix stride (u16) -> 144B rows, 16B-aligned frags

typedef __attribute__((ext_vector_type(8))) short bf16x8;
typedef __attribute__((ext_vector_type(4))) float f32x4;

static __device__ __forceinline__ ushort f2b(float x) {
  union { float f; unsigned u; } c; c.f = x;
  unsigned u = c.u;
  return (ushort)((u + 0x7FFFu + ((u >> 16) & 1u)) >> 16);   // RNE
}
static __device__ __forceinline__ float b2f(ushort h) {
  union { unsigned u; float f; } c; c.u = ((unsigned)h) << 16; return c.f;
}

#define LD8(p, r, c) (*(const bf16x8*)&(p)[(size_t)(r) * S + (c)])
#define MFMA(a, bm, acc) __builtin_amdgcn_mfma_f32_16x16x32_bf16((a), (bm), (acc), 0, 0, 0)

// ---------------------------------------------------------------------------
// 4-buffer GEMM body (k_pre1 only): C = A@B^T (BT=1) or A@B (BT=0),
// hi/lo bf16 3-term MFMA (~f32). One 64x64 tile per call.
// ---------------------------------------------------------------------------
template <int BT, int BF16OUT>
__device__ __forceinline__ void gemm_body(ushort* arena,
                                          const float* __restrict__ A,
                                          const float* __restrict__ B,
                                          void* __restrict__ Cout,
                                          int M, int AS, int BS, int KG,
                                          int mb, int nb) {
  ushort* Ahi = arena;
  ushort* Alo = arena + L * S;
  ushort* Bhi = arena + 2 * L * S;
  ushort* Blo = arena + 3 * L * S;
  int tid = threadIdx.x;
  int lane = tid & 63, w = tid >> 6;
  int lrow = lane & 15, lk = lane >> 4;

  f32x4 acc[4];
  #pragma unroll
  for (int t = 0; t < 4; ++t) acc[t] = (f32x4){0.f, 0.f, 0.f, 0.f};

  for (int kc = 0; kc < 5; ++kc) {
    int k0 = 64 * kc;
    for (int idx = tid; idx < 64 * 16; idx += 256) {
      int r = idx >> 4, c4 = (idx & 15) * 4;
      int m = mb * 64 + r, k = k0 + c4;
      float4 v = make_float4(0.f, 0.f, 0.f, 0.f);
      if (m < M && k < KG) v = *(const float4*)&A[(size_t)m * AS + k];
      ushort4 h4, l4;
      h4.x = f2b(v.x); l4.x = f2b(v.x - b2f(h4.x));
      h4.y = f2b(v.y); l4.y = f2b(v.y - b2f(h4.y));
      h4.z = f2b(v.z); l4.z = f2b(v.z - b2f(h4.z));
      h4.w = f2b(v.w); l4.w = f2b(v.w - b2f(h4.w));
      *(ushort4*)&Ahi[r * S + c4] = h4;
      *(ushort4*)&Alo[r * S + c4] = l4;
    }
    for (int idx = tid; idx < 64 * 16; idx += 256) {
      int r = idx >> 4, c4 = (idx & 15) * 4;
      if (BT) {
        int n = nb * 64 + r, k = k0 + c4;
        float4 v = make_float4(0.f, 0.f, 0.f, 0.f);
        if (n < 300 && k < 300) v = *(const float4*)&B[(size_t)n * BS + k];
        ushort4 h4, l4;
        h4.x = f2b(v.x); l4.x = f2b(v.x - b2f(h4.x));
        h4.y = f2b(v.y); l4.y = f2b(v.y - b2f(h4.y));
        h4.z = f2b(v.z); l4.z = f2b(v.z - b2f(h4.z));
        h4.w = f2b(v.w); l4.w = f2b(v.w - b2f(h4.w));
        *(ushort4*)&Bhi[r * S + c4] = h4;
        *(ushort4*)&Blo[r * S + c4] = l4;
      } else {
        int k = k0 + r, n = nb * 64 + c4;
        float4 v = make_float4(0.f, 0.f, 0.f, 0.f);
        if (k < 300 && n < 300) v = *(const float4*)&B[(size_t)k * BS + n];
        #pragma unroll
        for (int q = 0; q < 4; ++q) {
          float xq = (q == 0) ? v.x : (q == 1) ? v.y : (q == 2) ? v.z : v.w;
          ushort hi = f2b(xq);
          Bhi[(size_t)(c4 + q) * S + r] = hi;
          Blo[(size_t)(c4 + q) * S + r] = f2b(xq - b2f(hi));
        }
      }
    }
    __syncthreads();
    #pragma unroll
    for (int ks = 0; ks < 2; ++ks) {
      bf16x8 ah = LD8(Ahi, 16 * w + lrow, 32 * ks + 8 * lk);
      bf16x8 al = LD8(Alo, 16 * w + lrow, 32 * ks + 8 * lk);
      #pragma unroll
      for (int t = 0; t < 4; ++t) {
        bf16x8 bh = LD8(Bhi, 16 * t + lrow, 32 * ks + 8 * lk);
        bf16x8 bl = LD8(Blo, 16 * t + lrow, 32 * ks + 8 * lk);
        acc[t] = MFMA(ah, bh, acc[t]);
        acc[t] = MFMA(ah, bl, acc[t]);
        acc[t] = MFMA(al, bh, acc[t]);
      }
    }
    __syncthreads();
  }
  #pragma unroll
  for (int t = 0; t < 4; ++t) {
    int n = nb * 64 + 16 * t + lrow;
    int mbase = mb * 64 + 16 * w + 4 * lk;
    if (n < TSTR) {
      #pragma unroll
      for (int r = 0; r < 4; ++r) {
        int m = mbase + r;
        if (m < M) {
          if (BF16OUT) ((ushort*)Cout)[(size_t)m * TSTR + n] = f2b(acc[t][r]);
          else         ((float*)Cout)[(size_t)m * TSTR + n] = acc[t][r];
        }
      }
    }
  }
}

// ---------------------------------------------------------------------------
// 2-buffer GEMM body (k_pre2's t0bf = E1 @ T^T, bf16 out). Same arithmetic,
// A-frags pass through regs so only 2 LDS buffers are needed (4 bars/kc).
// ---------------------------------------------------------------------------
__device__ __forceinline__ void gemm2_body(ushort* arena,
                                           const float* __restrict__ A,
                                           const float* __restrict__ B,
                                           ushort* __restrict__ Cout,
                                           int M, int mb, int nb) {
  ushort* buf0 = arena;
  ushort* buf1 = arena + L * S;
  int tid = threadIdx.x;
  int lane = tid & 63, w = tid >> 6;
  int lrow = lane & 15, lk = lane >> 4;

  f32x4 acc[4];
  #pragma unroll
  for (int t = 0; t < 4; ++t) acc[t] = (f32x4){0.f, 0.f, 0.f, 0.f};

  for (int kc = 0; kc < 5; ++kc) {
    int k0 = 64 * kc;
    // stage A tile hi/lo
    for (int idx = tid; idx < 64 * 16; idx += 256) {
      int r = idx >> 4, c4 = (idx & 15) * 4;
      int m = mb * 64 + r, k = k0 + c4;
      float4 v = make_float4(0.f, 0.f, 0.f, 0.f);
      if (m < M && k < TSTR) v = *(const float4*)&A[(size_t)m * TSTR + k];
      ushort4 h4, l4;
      h4.x = f2b(v.x); l4.x = f2b(v.x - b2f(h4.x));
      h4.y = f2b(v.y); l4.y = f2b(v.y - b2f(h4.y));
      h4.z = f2b(v.z); l4.z = f2b(v.z - b2f(h4.z));
      h4.w = f2b(v.w); l4.w = f2b(v.w - b2f(h4.w));
      *(ushort4*)&buf0[r * S + c4] = h4;
      *(ushort4*)&buf1[r * S + c4] = l4;
    }
    __syncthreads();
    bf16x8 ah0 = LD8(buf0, 16 * w + lrow, 8 * lk);
    bf16x8 ah1 = LD8(buf0, 16 * w + lrow, 32 + 8 * lk);
    bf16x8 al0 = LD8(buf1, 16 * w + lrow, 8 * lk);
    bf16x8 al1 = LD8(buf1, 16 * w + lrow, 32 + 8 * lk);
    __syncthreads();
    // stage B tile hi/lo (B^T operand: frag[n][k] = B[n][k], B stride TSTR)
    for (int idx = tid; idx < 64 * 16; idx += 256) {
      int r = idx >> 4, c4 = (idx & 15) * 4;
      int n = nb * 64 + r, k = k0 + c4;
      float4 v = make_float4(0.f, 0.f, 0.f, 0.f);
      if (n < 300 && k < TSTR) v = *(const float4*)&B[(size_t)n * TSTR + k];
      ushort4 h4, l4;
      h4.x = f2b(v.x); l4.x = f2b(v.x - b2f(h4.x));
      h4.y = f2b(v.y); l4.y = f2b(v.y - b2f(h4.y));
      h4.z = f2b(v.z); l4.z = f2b(v.z - b2f(h4.z));
      h4.w = f2b(v.w); l4.w = f2b(v.w - b2f(h4.w));
      *(ushort4*)&buf0[r * S + c4] = h4;
      *(ushort4*)&buf1[r * S + c4] = l4;
    }
    __syncthreads();
    #pragma unroll
    for (int t = 0; t < 4; ++t) {
      bf16x8 bh = LD8(buf0, 16 * t + lrow, 8 * lk);
      bf16x8 bl = LD8(buf1, 16 * t + lrow, 8 * lk);
      acc[t] = MFMA(ah0, bh, acc[t]);
      acc[t] = MFMA(ah0, bl, acc[t]);
      acc[t] = MFMA(al0, bh, acc[t]);
      bh = LD8(buf0, 16 * t + lrow, 32 + 8 * lk);
      bl = LD8(buf1, 16 * t + lrow, 32 + 8 * lk);
      acc[t] = MFMA(ah1, bh, acc[t]);
      acc[t] = MFMA(ah1, bl, acc[t]);
      acc[t] = MFMA(al1, bh, acc[t]);
    }
    __syncthreads();
  }
  #pragma unroll
  for (int t = 0; t < 4; ++t) {
    int n = nb * 64 + 16 * t + lrow;
    int mbase = mb * 64 + 16 * w + 4 * lk;
    if (n < TSTR) {
      #pragma unroll
      for (int r = 0; r < 4; ++r) {
        int m = mbase + r;
        if (m < M) Cout[(size_t)m * TSTR + n] = f2b(acc[t][r]);
      }
    }
  }
}

// ---------------------------------------------------------------------------
// Launch 1: [0,25) T = W3@W2 | [25,155) E1 = emb@W1^T | [155,1179) u8 quant
// ---------------------------------------------------------------------------
__global__ __launch_bounds__(256, 4) void k_pre1(const float* __restrict__ in_adj,
                                                 unsigned char* __restrict__ adj8,
                                                 const float* __restrict__ emb,
                                                 const float* __restrict__ lw,
                                                 float* __restrict__ E1,
                                                 float* __restrict__ T) {
  __shared__ __align__(16) ushort arena[4 * L * S];
  const float* W1 = lw;
  const float* W2 = lw + (size_t)EMB * EMB;
  const float* W3 = lw + 2 * (size_t)EMB * EMB;
  int bid = blockIdx.x;
  if (bid < 25) {
    gemm_body<0, 0>(arena, W3, W2, T, 300, 300, 300, 300, bid / 5, bid % 5);
  } else if (bid < 155) {
    int rid = bid - 25;
    gemm_body<1, 0>(arena, emb, W1, E1, NN, 300, 300, 300, rid % 26, rid / 26);
  } else {
    int b2 = bid - 155;
    const int total = NN * NN;           // 2563201
    const int n4 = total >> 2;
    int i = b2 * 256 + threadIdx.x;
    for (int i4 = i; i4 < n4; i4 += 1024 * 256) {
      float4 v = *(const float4*)&in_adj[4 * i4];
      uchar4 q;
      q.x = (unsigned char)__float2int_rn(v.x * 255.f);
      q.y = (unsigned char)__float2int_rn(v.y * 255.f);
      q.z = (unsigned char)__float2int_rn(v.z * 255.f);
      q.w = (unsigned char)__float2int_rn(v.w * 255.f);
      *(uchar4*)&adj8[4 * i4] = q;
    }
    if (i == 0)
      adj8[total - 1] = (unsigned char)__float2int_rn(in_adj[total - 1] * 255.f);
  }
}

// ---------------------------------------------------------------------------
// A^3 body, 2-buffer LDS: A = norm(gather_u8 + I); A2 = A@A; A3 = A@A2,
// hi/lo 3-term MFMA. Writes A3 (64x64 bf16 rows) to a3g[b].
// ---------------------------------------------------------------------------
__device__ __forceinline__ void a3_body(ushort* arena, int* lab, float (*ps)[L],
                                        float* dv, const int* __restrict__ labels,
                                        const unsigned char* __restrict__ adj8,
                                        ushort* __restrict__ a3g, int b) {
  ushort* buf0 = arena;
  ushort* buf1 = arena + L * S;
  int tid = threadIdx.x, j = tid & 63, g = tid >> 6;
  if (tid < L) lab[tid] = labels[(size_t)b * L + tid];
  __syncthreads();
  int labj = lab[j];

  float raw[16];
  float cs = 0.f;
  #pragma unroll
  for (int q = 0; q < 16; ++q) {
    int i = g + 4 * q;
    float v = (float)adj8[(size_t)lab[i] * NN + labj];
    v += (i == j) ? 255.f : 0.f;
    raw[q] = v; cs += v;
  }
  ps[g][j] = cs;
  __syncthreads();
  if (tid < L) dv[tid] = 1.f / sqrtf(ps[0][tid] + ps[1][tid] + ps[2][tid] + ps[3][tid]);
  __syncthreads();

  // A rows (hi/lo) into buf0/buf1; keep scaled values in regs
  float dj = dv[j];
  #pragma unroll
  for (int q = 0; q < 16; ++q) {
    int i = g + 4 * q;
    float a = raw[q] * dv[i] * dj;
    raw[q] = a;
    ushort hi = f2b(a);
    buf0[(size_t)i * S + j] = hi;
    buf1[(size_t)i * S + j] = f2b(a - b2f(hi));
  }
  __syncthreads();

  int lane = tid & 63, w = tid >> 6;
  int lrow = lane & 15, lk = lane >> 4;
  int m0 = 16 * w;

  bf16x8 ah0 = LD8(buf0, m0 + lrow, 8 * lk);
  bf16x8 ah1 = LD8(buf0, m0 + lrow, 32 + 8 * lk);
  bf16x8 al0 = LD8(buf1, m0 + lrow, 8 * lk);
  bf16x8 al1 = LD8(buf1, m0 + lrow, 32 + 8 * lk);
  __syncthreads();

  // overwrite with A^T (hi/lo)
  #pragma unroll
  for (int q = 0; q < 16; ++q) {
    int i = g + 4 * q;
    float a = raw[q];
    ushort hi = f2b(a);
    buf0[(size_t)j * S + i] = hi;
    buf1[(size_t)j * S + i] = f2b(a - b2f(hi));
  }
  __syncthreads();

  // A2 = A @ A -> overwrite buf0/1 with A2^T
  {
    f32x4 acc[4];
    #pragma unroll
    for (int t = 0; t < 4; ++t) {
      f32x4 a = {0.f, 0.f, 0.f, 0.f};
      bf16x8 bh = LD8(buf0, 16 * t + lrow, 8 * lk);
      bf16x8 bl = LD8(buf1, 16 * t + lrow, 8 * lk);
      a = MFMA(ah0, bh, a); a = MFMA(ah0, bl, a); a = MFMA(al0, bh, a);
      bh = LD8(buf0, 16 * t + lrow, 32 + 8 * lk);
      bl = LD8(buf1, 16 * t + lrow, 32 + 8 * lk);
      a = MFMA(ah1, bh, a); a = MFMA(ah1, bl, a); a = MFMA(al1, bh, a);
      acc[t] = a;
    }
    __syncthreads();
    #pragma unroll
    for (int t = 0; t < 4; ++t) {
      ushort4 h4, l4;
      float x;
      x = acc[t][0]; h4.x = f2b(x); l4.x = f2b(x - b2f(h4.x));
      x = acc[t][1]; h4.y = f2b(x); l4.y = f2b(x - b2f(h4.y));
      x = acc[t][2]; h4.z = f2b(x); l4.z = f2b(x - b2f(h4.z));
      x = acc[t][3]; h4.w = f2b(x); l4.w = f2b(x - b2f(h4.w));
      *(ushort4*)&buf0[(size_t)(16 * t + lrow) * S + m0 + 4 * lk] = h4;
      *(ushort4*)&buf1[(size_t)(16 * t + lrow) * S + m0 + 4 * lk] = l4;
    }
  }
  __syncthreads();

  // A3 = A @ A2 -> rows into buf0
  {
    f32x4 acc[4];
    #pragma unroll
    for (int t = 0; t < 4; ++t) {
      f32x4 a = {0.f, 0.f, 0.f, 0.f};
      bf16x8 bh = LD8(buf0, 16 * t + lrow, 8 * lk);
      bf16x8 bl = LD8(buf1, 16 * t + lrow, 8 * lk);
      a = MFMA(ah0, bh, a); a = MFMA(ah0, bl, a); a = MFMA(al0, bh, a);
      bh = LD8(buf0, 16 * t + lrow, 32 + 8 * lk);
      bl = LD8(buf1, 16 * t + lrow, 32 + 8 * lk);
      a = MFMA(ah1, bh, a); a = MFMA(ah1, bl, a); a = MFMA(al1, bh, a);
      acc[t] = a;
    }
    __syncthreads();
    #pragma unroll
    for (int t = 0; t < 4; ++t)
      #pragma unroll
      for (int r = 0; r < 4; ++r)
        buf0[(size_t)(m0 + 4 * lk + r) * S + 16 * t + lrow] = f2b(acc[t][r]);
  }
  __syncthreads();

  // coalesced store: a3g[b] = 64x64 bf16 row-major (8 KB)
  int4* dst = (int4*)(a3g + (size_t)b * (L * L));
  #pragma unroll
  for (int q = 0; q < 2; ++q) {
    int id = tid + 256 * q;
    int r = id >> 3, c8 = (id & 7) << 3;
    dst[id] = *(const int4*)&buf0[(size_t)r * S + c8];
  }
}

// ---------------------------------------------------------------------------
// Launch 2: [0,130) t0bf = E1 @ T^T (bf16, 2-buf)  |  [130,2178) A^3
// (t0bf tiles first so they don't tail the launch)
// ---------------------------------------------------------------------------
__global__ __launch_bounds__(256, 8) void k_pre2(const int* __restrict__ labels,
                                                 const unsigned char* __restrict__ adj8,
                                                 ushort* __restrict__ a3g,
                                                 const float* __restrict__ E1,
                                                 const float* __restrict__ T,
                                                 ushort* __restrict__ t0bf) {
  __shared__ __align__(16) ushort arena[2 * L * S];   // 18.4 KB
  __shared__ int   lab[L];
  __shared__ float ps[4][L];
  __shared__ float dv[L];
  int bid = blockIdx.x;
  if (bid < 130) {
    gemm2_body(arena, E1, T, t0bf, NN, bid % 26, bid / 26);
  } else {
    a3_body(arena, lab, ps, dv, labels, adj8, a3g, bid - 130);
  }
}

// ---------------------------------------------------------------------------
// Launch 3: out tiles. grid 8192. Decode puts a batch's 4 e-chunks on the
// SAME XCD (bid mod 8 fixed) AND within a 32-bid dispatch window, so the
// chunk-border partial lines of the 1200B-stride output merge in one L2
// while hot (R15's 2048-apart version left them cross-generation -> RMW).
//   b = (bid>>5)*8 + (bid&7),  c = (bid>>3)&3     (bijective over 8192)
// ---------------------------------------------------------------------------
__global__ __launch_bounds__(256, 8) void k_out(const int* __restrict__ labels,
                                                const ushort* __restrict__ a3g,
                                                const ushort* __restrict__ t0bf,
                                                float* __restrict__ out) {
  __shared__ __align__(16) ushort Tt[80 * S];    // 11520 B
  int bid = blockIdx.x;
  int b = ((bid >> 5) << 3) | (bid & 7);
  int c = (bid >> 3) & 3;
  int tid = threadIdx.x, j = tid & 63, g = tid >> 6;
  int labj = labels[(size_t)b * L + j];

  int lane = tid & 63, w = tid >> 6;
  int lrow = lane & 15, lk = lane >> 4;
  int m0 = 16 * w;

  // B-side A3 fragments straight from global (row stride 64 u16 = 128 B)
  const ushort* a3b = a3g + (size_t)b * (L * L) + (size_t)(m0 + lrow) * L;
  bf16x8 fb0 = *(const bf16x8*)&a3b[8 * lk];
  bf16x8 fb1 = *(const bf16x8*)&a3b[32 + 8 * lk];

  // stage Tt[e_local][j] = t0bf[lab[j]][80c + e_local]
  int base = 80 * c;
  int rows80 = (c == 3) ? 64 : 80;
  const ushort* trow = t0bf + (size_t)labj * TSTR + base;
  for (int e = 8 * g; e < rows80; e += 32) {
    union { int4 v; ushort u[8]; } uu;
    uu.v = *(const int4*)(trow + e);
    #pragma unroll
    for (int q = 0; q < 8; ++q) Tt[(size_t)(e + q) * S + j] = uu.u[q];
  }
  __syncthreads();

  float* orow = out + ((size_t)b * L + m0 + lrow) * EMB;
  int nt = (c == 3) ? 4 : 5;
  for (int t = 0; t < nt; ++t) {
    bf16x8 a0 = LD8(Tt, 16 * t + lrow, 8 * lk);
    bf16x8 a1 = LD8(Tt, 16 * t + lrow, 32 + 8 * lk);
    f32x4 o = {0.f, 0.f, 0.f, 0.f};
    o = MFMA(a0, fb0, o);
    o = MFMA(a1, fb1, o);
    int e0 = base + 16 * t + 4 * lk;
    if (e0 < EMB) *(f32x4*)&orow[e0] = o;
  }
}

// ---------------------------------------------------------------------------
extern "C" void kernel_launch(void* const* d_in, const int* in_sizes, int n_in,
                              void* d_out, int out_size, void* d_ws, size_t ws_size,
                              hipStream_t stream) {
  (void)in_sizes; (void)n_in; (void)out_size; (void)ws_size;
  const int*   labels = (const int*)d_in[0];
  const float* in_adj = (const float*)d_in[1];
  const float* emb    = (const float*)d_in[2];
  const float* lw     = (const float*)d_in[3];
  float* out = (float*)d_out;

  char* base = (char*)d_ws;
  unsigned char* adj8 = (unsigned char*)base;              // 2,563,201 B
  float*  T    = (float*)(base + 2563216);                 // 300x304 f32
  float*  E1   = (float*)(base + 2928016);                 // 1601x304 f32
  ushort* t0bf = (ushort*)(base + 4874832);                // 1601x304 bf16
  ushort* a3g  = (ushort*)(base + 5848240);                // 2048x64x64 bf16

  k_pre1<<<1179, 256, 0, stream>>>(in_adj, adj8, emb, lw, E1, T);
  k_pre2<<<2178, 256, 0, stream>>>(labels, adj8, a3g, E1, T, t0bf);
  k_out <<<4 * NB, 256, 0, stream>>>(labels, a3g, t0bf, out);
}

// Round 17
// 90.699 us; speedup vs baseline: 1.9073x; 1.0167x over previous
//
#include <hip/hip_runtime.h>

#define NN   1601
#define EMB  300
#define NB   2048
#define L    64
#define TSTR 304   // t0bf / T / E1 row stride (elements)
#define S    72    // LDS matrix stride (u16) -> 144B rows, 16B-aligned frags

typedef __attribute__((ext_vector_type(8))) short bf16x8;
typedef __attribute__((ext_vector_type(4))) float f32x4;

static __device__ __forceinline__ ushort f2b(float x) {
  union { float f; unsigned u; } c; c.f = x;
  unsigned u = c.u;
  return (ushort)((u + 0x7FFFu + ((u >> 16) & 1u)) >> 16);   // RNE
}
static __device__ __forceinline__ float b2f(ushort h) {
  union { unsigned u; float f; } c; c.u = ((unsigned)h) << 16; return c.f;
}

#define LD8(p, r, c) (*(const bf16x8*)&(p)[(size_t)(r) * S + (c)])
#define MFMA(a, bm, acc) __builtin_amdgcn_mfma_f32_16x16x32_bf16((a), (bm), (acc), 0, 0, 0)

// ---------------------------------------------------------------------------
// 4-buffer GEMM body (k_pre1 only): C = A@B^T (BT=1) or A@B (BT=0),
// hi/lo bf16 3-term MFMA (~f32). One 64x64 tile per call.
// ---------------------------------------------------------------------------
template <int BT, int BF16OUT>
__device__ __forceinline__ void gemm_body(ushort* arena,
                                          const float* __restrict__ A,
                                          const float* __restrict__ B,
                                          void* __restrict__ Cout,
                                          int M, int AS, int BS, int KG,
                                          int mb, int nb) {
  ushort* Ahi = arena;
  ushort* Alo = arena + L * S;
  ushort* Bhi = arena + 2 * L * S;
  ushort* Blo = arena + 3 * L * S;
  int tid = threadIdx.x;
  int lane = tid & 63, w = tid >> 6;
  int lrow = lane & 15, lk = lane >> 4;

  f32x4 acc[4];
  #pragma unroll
  for (int t = 0; t < 4; ++t) acc[t] = (f32x4){0.f, 0.f, 0.f, 0.f};

  for (int kc = 0; kc < 5; ++kc) {
    int k0 = 64 * kc;
    for (int idx = tid; idx < 64 * 16; idx += 256) {
      int r = idx >> 4, c4 = (idx & 15) * 4;
      int m = mb * 64 + r, k = k0 + c4;
      float4 v = make_float4(0.f, 0.f, 0.f, 0.f);
      if (m < M && k < KG) v = *(const float4*)&A[(size_t)m * AS + k];
      ushort4 h4, l4;
      h4.x = f2b(v.x); l4.x = f2b(v.x - b2f(h4.x));
      h4.y = f2b(v.y); l4.y = f2b(v.y - b2f(h4.y));
      h4.z = f2b(v.z); l4.z = f2b(v.z - b2f(h4.z));
      h4.w = f2b(v.w); l4.w = f2b(v.w - b2f(h4.w));
      *(ushort4*)&Ahi[r * S + c4] = h4;
      *(ushort4*)&Alo[r * S + c4] = l4;
    }
    for (int idx = tid; idx < 64 * 16; idx += 256) {
      int r = idx >> 4, c4 = (idx & 15) * 4;
      if (BT) {
        int n = nb * 64 + r, k = k0 + c4;
        float4 v = make_float4(0.f, 0.f, 0.f, 0.f);
        if (n < 300 && k < 300) v = *(const float4*)&B[(size_t)n * BS + k];
        ushort4 h4, l4;
        h4.x = f2b(v.x); l4.x = f2b(v.x - b2f(h4.x));
        h4.y = f2b(v.y); l4.y = f2b(v.y - b2f(h4.y));
        h4.z = f2b(v.z); l4.z = f2b(v.z - b2f(h4.z));
        h4.w = f2b(v.w); l4.w = f2b(v.w - b2f(h4.w));
        *(ushort4*)&Bhi[r * S + c4] = h4;
        *(ushort4*)&Blo[r * S + c4] = l4;
      } else {
        int k = k0 + r, n = nb * 64 + c4;
        float4 v = make_float4(0.f, 0.f, 0.f, 0.f);
        if (k < 300 && n < 300) v = *(const float4*)&B[(size_t)k * BS + n];
        #pragma unroll
        for (int q = 0; q < 4; ++q) {
          float xq = (q == 0) ? v.x : (q == 1) ? v.y : (q == 2) ? v.z : v.w;
          ushort hi = f2b(xq);
          Bhi[(size_t)(c4 + q) * S + r] = hi;
          Blo[(size_t)(c4 + q) * S + r] = f2b(xq - b2f(hi));
        }
      }
    }
    __syncthreads();
    #pragma unroll
    for (int ks = 0; ks < 2; ++ks) {
      bf16x8 ah = LD8(Ahi, 16 * w + lrow, 32 * ks + 8 * lk);
      bf16x8 al = LD8(Alo, 16 * w + lrow, 32 * ks + 8 * lk);
      #pragma unroll
      for (int t = 0; t < 4; ++t) {
        bf16x8 bh = LD8(Bhi, 16 * t + lrow, 32 * ks + 8 * lk);
        bf16x8 bl = LD8(Blo, 16 * t + lrow, 32 * ks + 8 * lk);
        acc[t] = MFMA(ah, bh, acc[t]);
        acc[t] = MFMA(ah, bl, acc[t]);
        acc[t] = MFMA(al, bh, acc[t]);
      }
    }
    __syncthreads();
  }
  #pragma unroll
  for (int t = 0; t < 4; ++t) {
    int n = nb * 64 + 16 * t + lrow;
    int mbase = mb * 64 + 16 * w + 4 * lk;
    if (n < TSTR) {
      #pragma unroll
      for (int r = 0; r < 4; ++r) {
        int m = mbase + r;
        if (m < M) {
          if (BF16OUT) ((ushort*)Cout)[(size_t)m * TSTR + n] = f2b(acc[t][r]);
          else         ((float*)Cout)[(size_t)m * TSTR + n] = acc[t][r];
        }
      }
    }
  }
}

// ---------------------------------------------------------------------------
// 2-buffer GEMM body (k_pre2's t0bf = E1 @ T^T, bf16 out). Same arithmetic,
// A-frags pass through regs so only 2 LDS buffers are needed (4 bars/kc).
// ---------------------------------------------------------------------------
__device__ __forceinline__ void gemm2_body(ushort* arena,
                                           const float* __restrict__ A,
                                           const float* __restrict__ B,
                                           ushort* __restrict__ Cout,
                                           int M, int mb, int nb) {
  ushort* buf0 = arena;
  ushort* buf1 = arena + L * S;
  int tid = threadIdx.x;
  int lane = tid & 63, w = tid >> 6;
  int lrow = lane & 15, lk = lane >> 4;

  f32x4 acc[4];
  #pragma unroll
  for (int t = 0; t < 4; ++t) acc[t] = (f32x4){0.f, 0.f, 0.f, 0.f};

  for (int kc = 0; kc < 5; ++kc) {
    int k0 = 64 * kc;
    // stage A tile hi/lo
    for (int idx = tid; idx < 64 * 16; idx += 256) {
      int r = idx >> 4, c4 = (idx & 15) * 4;
      int m = mb * 64 + r, k = k0 + c4;
      float4 v = make_float4(0.f, 0.f, 0.f, 0.f);
      if (m < M && k < TSTR) v = *(const float4*)&A[(size_t)m * TSTR + k];
      ushort4 h4, l4;
      h4.x = f2b(v.x); l4.x = f2b(v.x - b2f(h4.x));
      h4.y = f2b(v.y); l4.y = f2b(v.y - b2f(h4.y));
      h4.z = f2b(v.z); l4.z = f2b(v.z - b2f(h4.z));
      h4.w = f2b(v.w); l4.w = f2b(v.w - b2f(h4.w));
      *(ushort4*)&buf0[r * S + c4] = h4;
      *(ushort4*)&buf1[r * S + c4] = l4;
    }
    __syncthreads();
    bf16x8 ah0 = LD8(buf0, 16 * w + lrow, 8 * lk);
    bf16x8 ah1 = LD8(buf0, 16 * w + lrow, 32 + 8 * lk);
    bf16x8 al0 = LD8(buf1, 16 * w + lrow, 8 * lk);
    bf16x8 al1 = LD8(buf1, 16 * w + lrow, 32 + 8 * lk);
    __syncthreads();
    // stage B tile hi/lo (B^T operand: frag[n][k] = B[n][k], B stride TSTR)
    for (int idx = tid; idx < 64 * 16; idx += 256) {
      int r = idx >> 4, c4 = (idx & 15) * 4;
      int n = nb * 64 + r, k = k0 + c4;
      float4 v = make_float4(0.f, 0.f, 0.f, 0.f);
      if (n < 300 && k < TSTR) v = *(const float4*)&B[(size_t)n * TSTR + k];
      ushort4 h4, l4;
      h4.x = f2b(v.x); l4.x = f2b(v.x - b2f(h4.x));
      h4.y = f2b(v.y); l4.y = f2b(v.y - b2f(h4.y));
      h4.z = f2b(v.z); l4.z = f2b(v.z - b2f(h4.z));
      h4.w = f2b(v.w); l4.w = f2b(v.w - b2f(h4.w));
      *(ushort4*)&buf0[r * S + c4] = h4;
      *(ushort4*)&buf1[r * S + c4] = l4;
    }
    __syncthreads();
    #pragma unroll
    for (int t = 0; t < 4; ++t) {
      bf16x8 bh = LD8(buf0, 16 * t + lrow, 8 * lk);
      bf16x8 bl = LD8(buf1, 16 * t + lrow, 8 * lk);
      acc[t] = MFMA(ah0, bh, acc[t]);
      acc[t] = MFMA(ah0, bl, acc[t]);
      acc[t] = MFMA(al0, bh, acc[t]);
      bh = LD8(buf0, 16 * t + lrow, 32 + 8 * lk);
      bl = LD8(buf1, 16 * t + lrow, 32 + 8 * lk);
      acc[t] = MFMA(ah1, bh, acc[t]);
      acc[t] = MFMA(ah1, bl, acc[t]);
      acc[t] = MFMA(al1, bh, acc[t]);
    }
    __syncthreads();
  }
  #pragma unroll
  for (int t = 0; t < 4; ++t) {
    int n = nb * 64 + 16 * t + lrow;
    int mbase = mb * 64 + 16 * w + 4 * lk;
    if (n < TSTR) {
      #pragma unroll
      for (int r = 0; r < 4; ++r) {
        int m = mbase + r;
        if (m < M) Cout[(size_t)m * TSTR + n] = f2b(acc[t][r]);
      }
    }
  }
}

// ---------------------------------------------------------------------------
// Launch 1: [0,25) T = W3@W2 | [25,155) E1 = emb@W1^T | [155,1179) u8 quant
// ---------------------------------------------------------------------------
__global__ __launch_bounds__(256, 4) void k_pre1(const float* __restrict__ in_adj,
                                                 unsigned char* __restrict__ adj8,
                                                 const float* __restrict__ emb,
                                                 const float* __restrict__ lw,
                                                 float* __restrict__ E1,
                                                 float* __restrict__ T) {
  __shared__ __align__(16) ushort arena[4 * L * S];
  const float* W1 = lw;
  const float* W2 = lw + (size_t)EMB * EMB;
  const float* W3 = lw + 2 * (size_t)EMB * EMB;
  int bid = blockIdx.x;
  if (bid < 25) {
    gemm_body<0, 0>(arena, W3, W2, T, 300, 300, 300, 300, bid / 5, bid % 5);
  } else if (bid < 155) {
    int rid = bid - 25;
    gemm_body<1, 0>(arena, emb, W1, E1, NN, 300, 300, 300, rid % 26, rid / 26);
  } else {
    int b2 = bid - 155;
    const int total = NN * NN;           // 2563201
    const int n4 = total >> 2;
    int i = b2 * 256 + threadIdx.x;
    for (int i4 = i; i4 < n4; i4 += 1024 * 256) {
      float4 v = *(const float4*)&in_adj[4 * i4];
      uchar4 q;
      q.x = (unsigned char)__float2int_rn(v.x * 255.f);
      q.y = (unsigned char)__float2int_rn(v.y * 255.f);
      q.z = (unsigned char)__float2int_rn(v.z * 255.f);
      q.w = (unsigned char)__float2int_rn(v.w * 255.f);
      *(uchar4*)&adj8[4 * i4] = q;
    }
    if (i == 0)
      adj8[total - 1] = (unsigned char)__float2int_rn(in_adj[total - 1] * 255.f);
  }
}

// ---------------------------------------------------------------------------
// A^3 body, 2-buffer LDS: A = norm(gather_u8 + I); A2 = A@A; A3 = A@A2,
// hi/lo 3-term MFMA. Writes A3 (64x64 bf16 rows) to a3g[b].
// ---------------------------------------------------------------------------
__device__ __forceinline__ void a3_body(ushort* arena, int* lab, float (*ps)[L],
                                        float* dv, const int* __restrict__ labels,
                                        const unsigned char* __restrict__ adj8,
                                        ushort* __restrict__ a3g, int b) {
  ushort* buf0 = arena;
  ushort* buf1 = arena + L * S;
  int tid = threadIdx.x, j = tid & 63, g = tid >> 6;
  if (tid < L) lab[tid] = labels[(size_t)b * L + tid];
  __syncthreads();
  int labj = lab[j];

  float raw[16];
  float cs = 0.f;
  #pragma unroll
  for (int q = 0; q < 16; ++q) {
    int i = g + 4 * q;
    float v = (float)adj8[(size_t)lab[i] * NN + labj];
    v += (i == j) ? 255.f : 0.f;
    raw[q] = v; cs += v;
  }
  ps[g][j] = cs;
  __syncthreads();
  if (tid < L) dv[tid] = 1.f / sqrtf(ps[0][tid] + ps[1][tid] + ps[2][tid] + ps[3][tid]);
  __syncthreads();

  // A rows (hi/lo) into buf0/buf1; keep scaled values in regs
  float dj = dv[j];
  #pragma unroll
  for (int q = 0; q < 16; ++q) {
    int i = g + 4 * q;
    float a = raw[q] * dv[i] * dj;
    raw[q] = a;
    ushort hi = f2b(a);
    buf0[(size_t)i * S + j] = hi;
    buf1[(size_t)i * S + j] = f2b(a - b2f(hi));
  }
  __syncthreads();

  int lane = tid & 63, w = tid >> 6;
  int lrow = lane & 15, lk = lane >> 4;
  int m0 = 16 * w;

  bf16x8 ah0 = LD8(buf0, m0 + lrow, 8 * lk);
  bf16x8 ah1 = LD8(buf0, m0 + lrow, 32 + 8 * lk);
  bf16x8 al0 = LD8(buf1, m0 + lrow, 8 * lk);
  bf16x8 al1 = LD8(buf1, m0 + lrow, 32 + 8 * lk);
  __syncthreads();

  // overwrite with A^T (hi/lo)
  #pragma unroll
  for (int q = 0; q < 16; ++q) {
    int i = g + 4 * q;
    float a = raw[q];
    ushort hi = f2b(a);
    buf0[(size_t)j * S + i] = hi;
    buf1[(size_t)j * S + i] = f2b(a - b2f(hi));
  }
  __syncthreads();

  // A2 = A @ A -> overwrite buf0/1 with A2^T
  {
    f32x4 acc[4];
    #pragma unroll
    for (int t = 0; t < 4; ++t) {
      f32x4 a = {0.f, 0.f, 0.f, 0.f};
      bf16x8 bh = LD8(buf0, 16 * t + lrow, 8 * lk);
      bf16x8 bl = LD8(buf1, 16 * t + lrow, 8 * lk);
      a = MFMA(ah0, bh, a); a = MFMA(ah0, bl, a); a = MFMA(al0, bh, a);
      bh = LD8(buf0, 16 * t + lrow, 32 + 8 * lk);
      bl = LD8(buf1, 16 * t + lrow, 32 + 8 * lk);
      a = MFMA(ah1, bh, a); a = MFMA(ah1, bl, a); a = MFMA(al1, bh, a);
      acc[t] = a;
    }
    __syncthreads();
    #pragma unroll
    for (int t = 0; t < 4; ++t) {
      ushort4 h4, l4;
      float x;
      x = acc[t][0]; h4.x = f2b(x); l4.x = f2b(x - b2f(h4.x));
      x = acc[t][1]; h4.y = f2b(x); l4.y = f2b(x - b2f(h4.y));
      x = acc[t][2]; h4.z = f2b(x); l4.z = f2b(x - b2f(h4.z));
      x = acc[t][3]; h4.w = f2b(x); l4.w = f2b(x - b2f(h4.w));
      *(ushort4*)&buf0[(size_t)(16 * t + lrow) * S + m0 + 4 * lk] = h4;
      *(ushort4*)&buf1[(size_t)(16 * t + lrow) * S + m0 + 4 * lk] = l4;
    }
  }
  __syncthreads();

  // A3 = A @ A2 -> rows into buf0
  {
    f32x4 acc[4];
    #pragma unroll
    for (int t = 0; t < 4; ++t) {
      f32x4 a = {0.f, 0.f, 0.f, 0.f};
      bf16x8 bh = LD8(buf0, 16 * t + lrow, 8 * lk);
      bf16x8 bl = LD8(buf1, 16 * t + lrow, 8 * lk);
      a = MFMA(ah0, bh, a); a = MFMA(ah0, bl, a); a = MFMA(al0, bh, a);
      bh = LD8(buf0, 16 * t + lrow, 32 + 8 * lk);
      bl = LD8(buf1, 16 * t + lrow, 32 + 8 * lk);
      a = MFMA(ah1, bh, a); a = MFMA(ah1, bl, a); a = MFMA(al1, bh, a);
      acc[t] = a;
    }
    __syncthreads();
    #pragma unroll
    for (int t = 0; t < 4; ++t)
      #pragma unroll
      for (int r = 0; r < 4; ++r)
        buf0[(size_t)(m0 + 4 * lk + r) * S + 16 * t + lrow] = f2b(acc[t][r]);
  }
  __syncthreads();

  // coalesced store: a3g[b] = 64x64 bf16 row-major (8 KB)
  int4* dst = (int4*)(a3g + (size_t)b * (L * L));
  #pragma unroll
  for (int q = 0; q < 2; ++q) {
    int id = tid + 256 * q;
    int r = id >> 3, c8 = (id & 7) << 3;
    dst[id] = *(const int4*)&buf0[(size_t)r * S + c8];
  }
}

// ---------------------------------------------------------------------------
// Launch 2: [0,130) t0bf = E1 @ T^T (bf16, 2-buf)  |  [130,2178) A^3
// (t0bf tiles first so they don't tail the launch)
// ---------------------------------------------------------------------------
__global__ __launch_bounds__(256, 8) void k_pre2(const int* __restrict__ labels,
                                                 const unsigned char* __restrict__ adj8,
                                                 ushort* __restrict__ a3g,
                                                 const float* __restrict__ E1,
                                                 const float* __restrict__ T,
                                                 ushort* __restrict__ t0bf) {
  __shared__ __align__(16) ushort arena[2 * L * S];   // 18.4 KB
  __shared__ int   lab[L];
  __shared__ float ps[4][L];
  __shared__ float dv[L];
  int bid = blockIdx.x;
  if (bid < 130) {
    gemm2_body(arena, E1, T, t0bf, NN, bid % 26, bid / 26);
  } else {
    a3_body(arena, lab, ps, dv, labels, adj8, a3g, bid - 130);
  }
}

// ---------------------------------------------------------------------------
// Launch 3: out tiles. grid 8192. Decode: b = (bid>>5)*8 + (bid&7),
// c = (bid>>3)&3 -> same XCD AND 32-bid window for a batch's 4 chunks (R16).
// Tt gather is ROW-RUN coalesced: consecutive lanes read consecutive 16B
// segments of the SAME t0 row (160B runs) instead of 64 scattered granules.
// ---------------------------------------------------------------------------
__global__ __launch_bounds__(256, 8) void k_out(const int* __restrict__ labels,
                                                const ushort* __restrict__ a3g,
                                                const ushort* __restrict__ t0bf,
                                                float* __restrict__ out) {
  __shared__ __align__(16) ushort Tt[80 * S];    // 11520 B
  int bid = blockIdx.x;
  int b = ((bid >> 5) << 3) | (bid & 7);
  int c = (bid >> 3) & 3;
  int tid = threadIdx.x;

  int lane = tid & 63, w = tid >> 6;
  int lrow = lane & 15, lk = lane >> 4;
  int m0 = 16 * w;

  // B-side A3 fragments straight from global (row stride 64 u16 = 128 B)
  const ushort* a3b = a3g + (size_t)b * (L * L) + (size_t)(m0 + lrow) * L;
  bf16x8 fb0 = *(const bf16x8*)&a3b[8 * lk];
  bf16x8 fb1 = *(const bf16x8*)&a3b[32 + 8 * lk];

  // stage Tt[e_local][r] = t0bf[lab[r]][80c + e_local], row-run coalesced:
  // idx -> (row r, 16B segment sg); nseg consecutive lanes share row r.
  int base = 80 * c;
  int rows80 = (c == 3) ? 64 : 80;
  int nseg = rows80 >> 3;                       // 10 (c<3) or 8 (c==3)
  const int* labp = labels + (size_t)b * L;
  for (int idx = tid; idx < 64 * nseg; idx += 256) {
    int r = idx / nseg, sg = idx - r * nseg;
    int lr = labp[r];                           // broadcast within seg-group
    union { int4 v; ushort u[8]; } uu;
    uu.v = *(const int4*)(t0bf + (size_t)lr * TSTR + base + 8 * sg);
    #pragma unroll
    for (int q = 0; q < 8; ++q) Tt[(size_t)(8 * sg + q) * S + r] = uu.u[q];
  }
  __syncthreads();

  float* orow = out + ((size_t)b * L + m0 + lrow) * EMB;
  int nt = (c == 3) ? 4 : 5;
  for (int t = 0; t < nt; ++t) {
    bf16x8 a0 = LD8(Tt, 16 * t + lrow, 8 * lk);
    bf16x8 a1 = LD8(Tt, 16 * t + lrow, 32 + 8 * lk);
    f32x4 o = {0.f, 0.f, 0.f, 0.f};
    o = MFMA(a0, fb0, o);
    o = MFMA(a1, fb1, o);
    int e0 = base + 16 * t + 4 * lk;
    if (e0 < EMB) *(f32x4*)&orow[e0] = o;
  }
}

// ---------------------------------------------------------------------------
extern "C" void kernel_launch(void* const* d_in, const int* in_sizes, int n_in,
                              void* d_out, int out_size, void* d_ws, size_t ws_size,
                              hipStream_t stream) {
  (void)in_sizes; (void)n_in; (void)out_size; (void)ws_size;
  const int*   labels = (const int*)d_in[0];
  const float* in_adj = (const float*)d_in[1];
  const float* emb    = (const float*)d_in[2];
  const float* lw     = (const float*)d_in[3];
  float* out = (float*)d_out;

  char* base = (char*)d_ws;
  unsigned char* adj8 = (unsigned char*)base;              // 2,563,201 B
  float*  T    = (float*)(base + 2563216);                 // 300x304 f32
  float*  E1   = (float*)(base + 2928016);                 // 1601x304 f32
  ushort* t0bf = (ushort*)(base + 4874832);                // 1601x304 bf16
  ushort* a3g  = (ushort*)(base + 5848240);                // 2048x64x64 bf16

  k_pre1<<<1179, 256, 0, stream>>>(in_adj, adj8, emb, lw, E1, T);
  k_pre2<<<2178, 256, 0, stream>>>(labels, adj8, a3g, E1, T, t0bf);
  k_out <<<4 * NB, 256, 0, stream>>>(labels, a3g, t0bf, out);
}

// Round 18
// 90.403 us; speedup vs baseline: 1.9135x; 1.0033x over previous
//
#include <hip/hip_runtime.h>

#define NN   1601
#define EMB  300
#define NB   2048
#define L    64
#define TSTR 304   // t0bf / T / E1 row stride (elements)
#define S    72    // LDS matrix stride (u16) -> 144B rows, 16B-aligned frags

typedef __attribute__((ext_vector_type(8))) short bf16x8;
typedef __attribute__((ext_vector_type(4))) float f32x4;

static __device__ __forceinline__ ushort f2b(float x) {
  union { float f; unsigned u; } c; c.f = x;
  unsigned u = c.u;
  return (ushort)((u + 0x7FFFu + ((u >> 16) & 1u)) >> 16);   // RNE
}
static __device__ __forceinline__ float b2f(ushort h) {
  union { unsigned u; float f; } c; c.u = ((unsigned)h) << 16; return c.f;
}

#define LD8(p, r, c) (*(const bf16x8*)&(p)[(size_t)(r) * S + (c)])
#define MFMA(a, bm, acc) __builtin_amdgcn_mfma_f32_16x16x32_bf16((a), (bm), (acc), 0, 0, 0)

// ---------------------------------------------------------------------------
// 4-buffer GEMM body (k_pre1 only): C = A@B^T (BT=1) or A@B (BT=0),
// hi/lo bf16 3-term MFMA (~f32). One 64x64 tile per call.
// ---------------------------------------------------------------------------
template <int BT, int BF16OUT>
__device__ __forceinline__ void gemm_body(ushort* arena,
                                          const float* __restrict__ A,
                                          const float* __restrict__ B,
                                          void* __restrict__ Cout,
                                          int M, int AS, int BS, int KG,
                                          int mb, int nb) {
  ushort* Ahi = arena;
  ushort* Alo = arena + L * S;
  ushort* Bhi = arena + 2 * L * S;
  ushort* Blo = arena + 3 * L * S;
  int tid = threadIdx.x;
  int lane = tid & 63, w = tid >> 6;
  int lrow = lane & 15, lk = lane >> 4;

  f32x4 acc[4];
  #pragma unroll
  for (int t = 0; t < 4; ++t) acc[t] = (f32x4){0.f, 0.f, 0.f, 0.f};

  for (int kc = 0; kc < 5; ++kc) {
    int k0 = 64 * kc;
    for (int idx = tid; idx < 64 * 16; idx += 256) {
      int r = idx >> 4, c4 = (idx & 15) * 4;
      int m = mb * 64 + r, k = k0 + c4;
      float4 v = make_float4(0.f, 0.f, 0.f, 0.f);
      if (m < M && k < KG) v = *(const float4*)&A[(size_t)m * AS + k];
      ushort4 h4, l4;
      h4.x = f2b(v.x); l4.x = f2b(v.x - b2f(h4.x));
      h4.y = f2b(v.y); l4.y = f2b(v.y - b2f(h4.y));
      h4.z = f2b(v.z); l4.z = f2b(v.z - b2f(h4.z));
      h4.w = f2b(v.w); l4.w = f2b(v.w - b2f(h4.w));
      *(ushort4*)&Ahi[r * S + c4] = h4;
      *(ushort4*)&Alo[r * S + c4] = l4;
    }
    for (int idx = tid; idx < 64 * 16; idx += 256) {
      int r = idx >> 4, c4 = (idx & 15) * 4;
      if (BT) {
        int n = nb * 64 + r, k = k0 + c4;
        float4 v = make_float4(0.f, 0.f, 0.f, 0.f);
        if (n < 300 && k < 300) v = *(const float4*)&B[(size_t)n * BS + k];
        ushort4 h4, l4;
        h4.x = f2b(v.x); l4.x = f2b(v.x - b2f(h4.x));
        h4.y = f2b(v.y); l4.y = f2b(v.y - b2f(h4.y));
        h4.z = f2b(v.z); l4.z = f2b(v.z - b2f(h4.z));
        h4.w = f2b(v.w); l4.w = f2b(v.w - b2f(h4.w));
        *(ushort4*)&Bhi[r * S + c4] = h4;
        *(ushort4*)&Blo[r * S + c4] = l4;
      } else {
        int k = k0 + r, n = nb * 64 + c4;
        float4 v = make_float4(0.f, 0.f, 0.f, 0.f);
        if (k < 300 && n < 300) v = *(const float4*)&B[(size_t)k * BS + n];
        #pragma unroll
        for (int q = 0; q < 4; ++q) {
          float xq = (q == 0) ? v.x : (q == 1) ? v.y : (q == 2) ? v.z : v.w;
          ushort hi = f2b(xq);
          Bhi[(size_t)(c4 + q) * S + r] = hi;
          Blo[(size_t)(c4 + q) * S + r] = f2b(xq - b2f(hi));
        }
      }
    }
    __syncthreads();
    #pragma unroll
    for (int ks = 0; ks < 2; ++ks) {
      bf16x8 ah = LD8(Ahi, 16 * w + lrow, 32 * ks + 8 * lk);
      bf16x8 al = LD8(Alo, 16 * w + lrow, 32 * ks + 8 * lk);
      #pragma unroll
      for (int t = 0; t < 4; ++t) {
        bf16x8 bh = LD8(Bhi, 16 * t + lrow, 32 * ks + 8 * lk);
        bf16x8 bl = LD8(Blo, 16 * t + lrow, 32 * ks + 8 * lk);
        acc[t] = MFMA(ah, bh, acc[t]);
        acc[t] = MFMA(ah, bl, acc[t]);
        acc[t] = MFMA(al, bh, acc[t]);
      }
    }
    __syncthreads();
  }
  #pragma unroll
  for (int t = 0; t < 4; ++t) {
    int n = nb * 64 + 16 * t + lrow;
    int mbase = mb * 64 + 16 * w + 4 * lk;
    if (n < TSTR) {
      #pragma unroll
      for (int r = 0; r < 4; ++r) {
        int m = mbase + r;
        if (m < M) {
          if (BF16OUT) ((ushort*)Cout)[(size_t)m * TSTR + n] = f2b(acc[t][r]);
          else         ((float*)Cout)[(size_t)m * TSTR + n] = acc[t][r];
        }
      }
    }
  }
}

// ---------------------------------------------------------------------------
// 2-buffer GEMM body (k_pre2's t0bf = E1 @ T^T, bf16 out). Same arithmetic,
// A-frags pass through regs so only 2 LDS buffers are needed (4 bars/kc).
// ---------------------------------------------------------------------------
__device__ __forceinline__ void gemm2_body(ushort* arena,
                                           const float* __restrict__ A,
                                           const float* __restrict__ B,
                                           ushort* __restrict__ Cout,
                                           int M, int mb, int nb) {
  ushort* buf0 = arena;
  ushort* buf1 = arena + L * S;
  int tid = threadIdx.x;
  int lane = tid & 63, w = tid >> 6;
  int lrow = lane & 15, lk = lane >> 4;

  f32x4 acc[4];
  #pragma unroll
  for (int t = 0; t < 4; ++t) acc[t] = (f32x4){0.f, 0.f, 0.f, 0.f};

  for (int kc = 0; kc < 5; ++kc) {
    int k0 = 64 * kc;
    // stage A tile hi/lo
    for (int idx = tid; idx < 64 * 16; idx += 256) {
      int r = idx >> 4, c4 = (idx & 15) * 4;
      int m = mb * 64 + r, k = k0 + c4;
      float4 v = make_float4(0.f, 0.f, 0.f, 0.f);
      if (m < M && k < TSTR) v = *(const float4*)&A[(size_t)m * TSTR + k];
      ushort4 h4, l4;
      h4.x = f2b(v.x); l4.x = f2b(v.x - b2f(h4.x));
      h4.y = f2b(v.y); l4.y = f2b(v.y - b2f(h4.y));
      h4.z = f2b(v.z); l4.z = f2b(v.z - b2f(h4.z));
      h4.w = f2b(v.w); l4.w = f2b(v.w - b2f(h4.w));
      *(ushort4*)&buf0[r * S + c4] = h4;
      *(ushort4*)&buf1[r * S + c4] = l4;
    }
    __syncthreads();
    bf16x8 ah0 = LD8(buf0, 16 * w + lrow, 8 * lk);
    bf16x8 ah1 = LD8(buf0, 16 * w + lrow, 32 + 8 * lk);
    bf16x8 al0 = LD8(buf1, 16 * w + lrow, 8 * lk);
    bf16x8 al1 = LD8(buf1, 16 * w + lrow, 32 + 8 * lk);
    __syncthreads();
    // stage B tile hi/lo (B^T operand: frag[n][k] = B[n][k], B stride TSTR)
    for (int idx = tid; idx < 64 * 16; idx += 256) {
      int r = idx >> 4, c4 = (idx & 15) * 4;
      int n = nb * 64 + r, k = k0 + c4;
      float4 v = make_float4(0.f, 0.f, 0.f, 0.f);
      if (n < 300 && k < TSTR) v = *(const float4*)&B[(size_t)n * TSTR + k];
      ushort4 h4, l4;
      h4.x = f2b(v.x); l4.x = f2b(v.x - b2f(h4.x));
      h4.y = f2b(v.y); l4.y = f2b(v.y - b2f(h4.y));
      h4.z = f2b(v.z); l4.z = f2b(v.z - b2f(h4.z));
      h4.w = f2b(v.w); l4.w = f2b(v.w - b2f(h4.w));
      *(ushort4*)&buf0[r * S + c4] = h4;
      *(ushort4*)&buf1[r * S + c4] = l4;
    }
    __syncthreads();
    #pragma unroll
    for (int t = 0; t < 4; ++t) {
      bf16x8 bh = LD8(buf0, 16 * t + lrow, 8 * lk);
      bf16x8 bl = LD8(buf1, 16 * t + lrow, 8 * lk);
      acc[t] = MFMA(ah0, bh, acc[t]);
      acc[t] = MFMA(ah0, bl, acc[t]);
      acc[t] = MFMA(al0, bh, acc[t]);
      bh = LD8(buf0, 16 * t + lrow, 32 + 8 * lk);
      bl = LD8(buf1, 16 * t + lrow, 32 + 8 * lk);
      acc[t] = MFMA(ah1, bh, acc[t]);
      acc[t] = MFMA(ah1, bl, acc[t]);
      acc[t] = MFMA(al1, bh, acc[t]);
    }
    __syncthreads();
  }
  #pragma unroll
  for (int t = 0; t < 4; ++t) {
    int n = nb * 64 + 16 * t + lrow;
    int mbase = mb * 64 + 16 * w + 4 * lk;
    if (n < TSTR) {
      #pragma unroll
      for (int r = 0; r < 4; ++r) {
        int m = mbase + r;
        if (m < M) Cout[(size_t)m * TSTR + n] = f2b(acc[t][r]);
      }
    }
  }
}

// ---------------------------------------------------------------------------
// Launch 1: [0,25) T = W3@W2 | [25,155) E1 = emb@W1^T | [155,1179) u8 quant
// ---------------------------------------------------------------------------
__global__ __launch_bounds__(256, 4) void k_pre1(const float* __restrict__ in_adj,
                                                 unsigned char* __restrict__ adj8,
                                                 const float* __restrict__ emb,
                                                 const float* __restrict__ lw,
                                                 float* __restrict__ E1,
                                                 float* __restrict__ T) {
  __shared__ __align__(16) ushort arena[4 * L * S];
  const float* W1 = lw;
  const float* W2 = lw + (size_t)EMB * EMB;
  const float* W3 = lw + 2 * (size_t)EMB * EMB;
  int bid = blockIdx.x;
  if (bid < 25) {
    gemm_body<0, 0>(arena, W3, W2, T, 300, 300, 300, 300, bid / 5, bid % 5);
  } else if (bid < 155) {
    int rid = bid - 25;
    gemm_body<1, 0>(arena, emb, W1, E1, NN, 300, 300, 300, rid % 26, rid / 26);
  } else {
    int b2 = bid - 155;
    const int total = NN * NN;           // 2563201
    const int n4 = total >> 2;
    int i = b2 * 256 + threadIdx.x;
    for (int i4 = i; i4 < n4; i4 += 1024 * 256) {
      float4 v = *(const float4*)&in_adj[4 * i4];
      uchar4 q;
      q.x = (unsigned char)__float2int_rn(v.x * 255.f);
      q.y = (unsigned char)__float2int_rn(v.y * 255.f);
      q.z = (unsigned char)__float2int_rn(v.z * 255.f);
      q.w = (unsigned char)__float2int_rn(v.w * 255.f);
      *(uchar4*)&adj8[4 * i4] = q;
    }
    if (i == 0)
      adj8[total - 1] = (unsigned char)__float2int_rn(in_adj[total - 1] * 255.f);
  }
}

// ---------------------------------------------------------------------------
// A^3 body, 1-term bf16 (R18): A = norm(gather_u8 + I) rounded to bf16;
// A2 = A@A, A3 = A@A2 in plain bf16 MFMA (16 MFMAs, 8 barriers).
// Error budget: ~2*2^-9 extra relative vs hi/lo -> absmax ~3-6e-3 < 1.05e-2.
// buf0: A rows -> A2^T ; buf1: A^T -> A3 rows.
// ---------------------------------------------------------------------------
__device__ __forceinline__ void a3_body(ushort* arena, int* lab, float (*ps)[L],
                                        float* dv, const int* __restrict__ labels,
                                        const unsigned char* __restrict__ adj8,
                                        ushort* __restrict__ a3g, int b) {
  ushort* buf0 = arena;
  ushort* buf1 = arena + L * S;
  int tid = threadIdx.x, j = tid & 63, g = tid >> 6;
  if (tid < L) lab[tid] = labels[(size_t)b * L + tid];
  __syncthreads();
  int labj = lab[j];

  float raw[16];
  float cs = 0.f;
  #pragma unroll
  for (int q = 0; q < 16; ++q) {
    int i = g + 4 * q;
    float v = (float)adj8[(size_t)lab[i] * NN + labj];
    v += (i == j) ? 255.f : 0.f;
    raw[q] = v; cs += v;
  }
  ps[g][j] = cs;
  __syncthreads();
  if (tid < L) dv[tid] = 1.f / sqrtf(ps[0][tid] + ps[1][tid] + ps[2][tid] + ps[3][tid]);
  __syncthreads();

  // A rows (bf16) -> buf0, A^T -> buf1
  float dj = dv[j];
  #pragma unroll
  for (int q = 0; q < 16; ++q) {
    int i = g + 4 * q;
    ushort hv = f2b(raw[q] * dv[i] * dj);
    buf0[(size_t)i * S + j] = hv;
    buf1[(size_t)j * S + i] = hv;
  }
  __syncthreads();

  int lane = tid & 63, w = tid >> 6;
  int lrow = lane & 15, lk = lane >> 4;
  int m0 = 16 * w;

  // A-side fragments of A rows (reused for A^2 and A^3)
  bf16x8 a0 = LD8(buf0, m0 + lrow, 8 * lk);
  bf16x8 a1 = LD8(buf0, m0 + lrow, 32 + 8 * lk);

  // A2 = A @ A (B-op = A^T tiles in buf1) -> A2^T into buf0
  f32x4 acc[4];
  #pragma unroll
  for (int t = 0; t < 4; ++t) {
    f32x4 a = {0.f, 0.f, 0.f, 0.f};
    a = MFMA(a0, LD8(buf1, 16 * t + lrow, 8 * lk), a);
    a = MFMA(a1, LD8(buf1, 16 * t + lrow, 32 + 8 * lk), a);
    acc[t] = a;
  }
  __syncthreads();   // all buf0-frag + buf1-tile reads done
  #pragma unroll
  for (int t = 0; t < 4; ++t) {
    ushort4 h4;
    h4.x = f2b(acc[t][0]); h4.y = f2b(acc[t][1]);
    h4.z = f2b(acc[t][2]); h4.w = f2b(acc[t][3]);
    // acc[t][r] = A2[m0+4lk+r][16t+lrow] -> A2^T[16t+lrow][m0+4lk+r]
    *(ushort4*)&buf0[(size_t)(16 * t + lrow) * S + m0 + 4 * lk] = h4;
  }
  __syncthreads();

  // A3 = A @ A2 (B-op = A2^T tiles in buf0) -> A3 rows into buf1
  #pragma unroll
  for (int t = 0; t < 4; ++t) {
    f32x4 a = {0.f, 0.f, 0.f, 0.f};
    a = MFMA(a0, LD8(buf0, 16 * t + lrow, 8 * lk), a);
    a = MFMA(a1, LD8(buf0, 16 * t + lrow, 32 + 8 * lk), a);
    acc[t] = a;
  }
  __syncthreads();   // buf0 reads done; buf1 dead since A2 phase
  #pragma unroll
  for (int t = 0; t < 4; ++t)
    #pragma unroll
    for (int r = 0; r < 4; ++r)
      buf1[(size_t)(m0 + 4 * lk + r) * S + 16 * t + lrow] = f2b(acc[t][r]);
  __syncthreads();

  // coalesced store: a3g[b] = 64x64 bf16 row-major (8 KB)
  int4* dst = (int4*)(a3g + (size_t)b * (L * L));
  #pragma unroll
  for (int q = 0; q < 2; ++q) {
    int id = tid + 256 * q;
    int r = id >> 3, c8 = (id & 7) << 3;
    dst[id] = *(const int4*)&buf1[(size_t)r * S + c8];
  }
}

// ---------------------------------------------------------------------------
// Launch 2: [0,130) t0bf = E1 @ T^T (bf16, 2-buf)  |  [130,2178) A^3
// (t0bf tiles first so they don't tail the launch)
// ---------------------------------------------------------------------------
__global__ __launch_bounds__(256, 8) void k_pre2(const int* __restrict__ labels,
                                                 const unsigned char* __restrict__ adj8,
                                                 ushort* __restrict__ a3g,
                                                 const float* __restrict__ E1,
                                                 const float* __restrict__ T,
                                                 ushort* __restrict__ t0bf) {
  __shared__ __align__(16) ushort arena[2 * L * S];   // 18.4 KB
  __shared__ int   lab[L];
  __shared__ float ps[4][L];
  __shared__ float dv[L];
  int bid = blockIdx.x;
  if (bid < 130) {
    gemm2_body(arena, E1, T, t0bf, NN, bid % 26, bid / 26);
  } else {
    a3_body(arena, lab, ps, dv, labels, adj8, a3g, bid - 130);
  }
}

// ---------------------------------------------------------------------------
// Launch 3: out tiles. grid 8192. Decode: b = (bid>>5)*8 + (bid&7),
// c = (bid>>3)&3 -> same XCD AND 32-bid window for a batch's 4 chunks (R16).
// Tt gather is ROW-RUN coalesced (R17).
// ---------------------------------------------------------------------------
__global__ __launch_bounds__(256, 8) void k_out(const int* __restrict__ labels,
                                                const ushort* __restrict__ a3g,
                                                const ushort* __restrict__ t0bf,
                                                float* __restrict__ out) {
  __shared__ __align__(16) ushort Tt[80 * S];    // 11520 B
  int bid = blockIdx.x;
  int b = ((bid >> 5) << 3) | (bid & 7);
  int c = (bid >> 3) & 3;
  int tid = threadIdx.x;

  int lane = tid & 63, w = tid >> 6;
  int lrow = lane & 15, lk = lane >> 4;
  int m0 = 16 * w;

  // B-side A3 fragments straight from global (row stride 64 u16 = 128 B)
  const ushort* a3b = a3g + (size_t)b * (L * L) + (size_t)(m0 + lrow) * L;
  bf16x8 fb0 = *(const bf16x8*)&a3b[8 * lk];
  bf16x8 fb1 = *(const bf16x8*)&a3b[32 + 8 * lk];

  // stage Tt[e_local][r] = t0bf[lab[r]][80c + e_local], row-run coalesced
  int base = 80 * c;
  int rows80 = (c == 3) ? 64 : 80;
  int nseg = rows80 >> 3;                       // 10 (c<3) or 8 (c==3)
  const int* labp = labels + (size_t)b * L;
  for (int idx = tid; idx < 64 * nseg; idx += 256) {
    int r = idx / nseg, sg = idx - r * nseg;
    int lr = labp[r];                           // broadcast within seg-group
    union { int4 v; ushort u[8]; } uu;
    uu.v = *(const int4*)(t0bf + (size_t)lr * TSTR + base + 8 * sg);
    #pragma unroll
    for (int q = 0; q < 8; ++q) Tt[(size_t)(8 * sg + q) * S + r] = uu.u[q];
  }
  __syncthreads();

  float* orow = out + ((size_t)b * L + m0 + lrow) * EMB;
  int nt = (c == 3) ? 4 : 5;
  for (int t = 0; t < nt; ++t) {
    bf16x8 a0 = LD8(Tt, 16 * t + lrow, 8 * lk);
    bf16x8 a1 = LD8(Tt, 16 * t + lrow, 32 + 8 * lk);
    f32x4 o = {0.f, 0.f, 0.f, 0.f};
    o = MFMA(a0, fb0, o);
    o = MFMA(a1, fb1, o);
    int e0 = base + 16 * t + 4 * lk;
    if (e0 < EMB) *(f32x4*)&orow[e0] = o;
  }
}

// ---------------------------------------------------------------------------
extern "C" void kernel_launch(void* const* d_in, const int* in_sizes, int n_in,
                              void* d_out, int out_size, void* d_ws, size_t ws_size,
                              hipStream_t stream) {
  (void)in_sizes; (void)n_in; (void)out_size; (void)ws_size;
  const int*   labels = (const int*)d_in[0];
  const float* in_adj = (const float*)d_in[1];
  const float* emb    = (const float*)d_in[2];
  const float* lw     = (const float*)d_in[3];
  float* out = (float*)d_out;

  char* base = (char*)d_ws;
  unsigned char* adj8 = (unsigned char*)base;              // 2,563,201 B
  float*  T    = (float*)(base + 2563216);                 // 300x304 f32
  float*  E1   = (float*)(base + 2928016);                 // 1601x304 f32
  ushort* t0bf = (ushort*)(base + 4874832);                // 1601x304 bf16
  ushort* a3g  = (ushort*)(base + 5848240);                // 2048x64x64 bf16

  k_pre1<<<1179, 256, 0, stream>>>(in_adj, adj8, emb, lw, E1, T);
  k_pre2<<<2178, 256, 0, stream>>>(labels, adj8, a3g, E1, T, t0bf);
  k_out <<<4 * NB, 256, 0, stream>>>(labels, a3g, t0bf, out);
}